// Round 4
// baseline (775.178 us; speedup 1.0000x reference)
//
#include <hip/hip_runtime.h>
#include <hip/hip_bf16.h>
#include <cstdint>
#include <cstddef>

using bf16 = __hip_bfloat16;
typedef __bf16 bf16x8 __attribute__((ext_vector_type(8)));
typedef float floatx4 __attribute__((ext_vector_type(4)));

#define B_  2
#define T_  4096
#define C_  2048
#define H_  16
#define HK_ 8
#define D_  128
#define W_  512
#define BT_ (B_*T_)

__device__ __forceinline__ void gload_lds16(const void* g, void* l) {
  __builtin_amdgcn_global_load_lds((const __attribute__((address_space(1))) void*)g,
                                   (__attribute__((address_space(3))) void*)l, 16, 0, 0);
}
__device__ __forceinline__ floatx4 mfma16(bf16x8 a, bf16x8 b, floatx4 c) {
  return __builtin_amdgcn_mfma_f32_16x16x32_bf16(a, b, c, 0, 0, 0);
}
__device__ __forceinline__ __bf16 f2b(float f) {
  union { bf16 h; __bf16 b; } u; u.h = __float2bfloat16(f); return u.b;
}
__device__ __forceinline__ bf16x8 load8(const bf16* p) {
  return *(const bf16x8*)(const void*)p;
}
__device__ __forceinline__ bf16x8 load8(const float* p) {
  float4 a = *(const float4*)(const void*)p;
  float4 b = *(const float4*)(const void*)(p + 4);
  bf16x8 r;
  r[0]=f2b(a.x); r[1]=f2b(a.y); r[2]=f2b(a.z); r[3]=f2b(a.w);
  r[4]=f2b(b.x); r[5]=f2b(b.y); r[6]=f2b(b.z); r[7]=f2b(b.w);
  return r;
}
__device__ __forceinline__ void store1(float* p, float v) { *p = v; }
__device__ __forceinline__ void store1(bf16*  p, float v) { *p = __float2bfloat16(v); }

// One-shot f32 -> bf16 conversion of x and the four weight matrices.
__global__ __launch_bounds__(256) void cvt_k(const float* __restrict__ x,
                                             const float* __restrict__ wq,
                                             const float* __restrict__ wk,
                                             const float* __restrict__ wv,
                                             const float* __restrict__ wproj,
                                             bf16* __restrict__ xb,
                                             bf16* __restrict__ wqb,
                                             bf16* __restrict__ wkb,
                                             bf16* __restrict__ wvb,
                                             bf16* __restrict__ wprojb) {
  const int b = blockIdx.x;
  const float* src; bf16* dst; size_t off;
  if (b < 8192)       { src = x;     dst = xb;     off = (size_t)b * 2048; }
  else if (b < 10240) { src = wq;    dst = wqb;    off = (size_t)(b-8192) * 2048; }
  else if (b < 11264) { src = wk;    dst = wkb;    off = (size_t)(b-10240) * 2048; }
  else if (b < 12288) { src = wv;    dst = wvb;    off = (size_t)(b-11264) * 2048; }
  else                { src = wproj; dst = wprojb; off = (size_t)(b-12288) * 2048; }
  const size_t i = off + (size_t)threadIdx.x * 8;
  *(bf16x8*)(void*)(dst + i) = load8(src + i);
}

// C[m][n] = sum_k A[m][k] * B[n][k], all-bf16 inputs, m97-style DMA staging.
template<typename TC>
__global__ __launch_bounds__(256) void gemm_bt(const bf16* __restrict__ A,
                                               const bf16* __restrict__ Bw,
                                               TC* __restrict__ Cc,
                                               int M, int N, int Kd) {
  __shared__ alignas(16) bf16 As[128*64];
  __shared__ alignas(16) bf16 Bs[128*64];
  const int tid = threadIdx.x;
  const int w = tid >> 6, lane = tid & 63;
  const int quad = lane >> 4, l16 = lane & 15;
  const int wm = (w & 1) * 64, wn = (w >> 1) * 64;
  const int m0 = blockIdx.y * 128, n0 = blockIdx.x * 128;
  const int srow = lane >> 3, sseg = lane & 7;

  floatx4 acc[4][4];
  #pragma unroll
  for (int i = 0; i < 4; ++i)
    #pragma unroll
    for (int j = 0; j < 4; ++j) acc[i][j] = (floatx4){0.f, 0.f, 0.f, 0.f};

  for (int k0 = 0; k0 < Kd; k0 += 64) {
    __syncthreads();
    #pragma unroll
    for (int i = 0; i < 4; ++i) {
      const int r  = w*32 + i*8 + srow;
      const int gs = (sseg ^ (r & 7)) * 8;
      gload_lds16(A  + (size_t)(m0 + r)*Kd + k0 + gs, As + (w*32 + i*8)*64);
      gload_lds16(Bw + (size_t)(n0 + r)*Kd + k0 + gs, Bs + (w*32 + i*8)*64);
    }
    __syncthreads();
    #pragma unroll
    for (int kk = 0; kk < 2; ++kk) {
      bf16x8 af[4], bfr[4];
      #pragma unroll
      for (int mt = 0; mt < 4; ++mt) {
        const int m = wm + mt*16 + l16;
        af[mt] = load8(As + m*64 + (((kk*4 + quad) ^ (m & 7)) * 8));
      }
      #pragma unroll
      for (int nt = 0; nt < 4; ++nt) {
        const int n = wn + nt*16 + l16;
        bfr[nt] = load8(Bs + n*64 + (((kk*4 + quad) ^ (n & 7)) * 8));
      }
      #pragma unroll
      for (int mt = 0; mt < 4; ++mt)
        #pragma unroll
        for (int nt = 0; nt < 4; ++nt)
          acc[mt][nt] = mfma16(af[mt], bfr[nt], acc[mt][nt]);
    }
  }

  #pragma unroll
  for (int mt = 0; mt < 4; ++mt)
    #pragma unroll
    for (int r = 0; r < 4; ++r) {
      const size_t row = (size_t)(m0 + wm + mt*16 + quad*4 + r);
      #pragma unroll
      for (int nt = 0; nt < 4; ++nt) {
        const int col = n0 + wn + nt*16 + l16;
        store1(Cc + row*N + col, acc[mt][nt][r]);
      }
    }
}

// grid (BT, 32), block 128.
__global__ __launch_bounds__(128) void fuse_k(const float* __restrict__ x,
                                              const float* __restrict__ ve,
                                              const float* __restrict__ cosb,
                                              const float* __restrict__ sinb,
                                              const float* __restrict__ wgate,
                                              bf16* __restrict__ Q,
                                              bf16* __restrict__ Kw,
                                              bf16* __restrict__ Vw) {
  const int tok = blockIdx.x;
  const int j   = blockIdx.y;
  const int t   = tok & (T_ - 1);
  const int tid = threadIdx.x;

  if (j < 24) {
    bf16* base = (j < 16) ? (Q + (size_t)tok * C_ + j * D_)
                          : (Kw + (size_t)tok * (HK_*D_) + (j - 16) * D_);
    const int d  = tid;
    const float v0 = __bfloat162float(base[d]);
    const float vp = __bfloat162float(base[d ^ 64]);
    const int dd = d & 63;
    const float c = cosb[t*64 + dd];
    const float s = sinb[t*64 + dd];
    const float val = (d < 64) ? (v0*c + vp*s) : (v0*c - vp*s);
    float ss = val * val;
    #pragma unroll
    for (int off = 1; off < 64; off <<= 1) ss += __shfl_xor(ss, off);
    __shared__ float red[2];
    if ((tid & 63) == 0) red[tid >> 6] = ss;
    __syncthreads();
    const float tot = red[0] + red[1];
    const float sc = rsqrtf(tot * (1.0f/128.0f) + 1.1920929e-7f);
    base[d] = __float2bfloat16(val * sc);
  } else {
    const int hk = j - 24;
    float z = 0.f;
    #pragma unroll
    for (int c = 0; c < 32; ++c)
      z += x[(size_t)tok * C_ + c] * wgate[hk*32 + c];
    const float gate = 2.0f / (1.0f + __expf(-z));
    const size_t idx = (size_t)tok * (HK_*D_) + hk * D_ + tid;
    Vw[idx] = __float2bfloat16(__bfloat162float(Vw[idx]) + gate * ve[idx]);
  }
}

// Flash-style windowed attention. grid (T/128, H, B), block 256 (4 waves).
// Round-0 structure (32-key tiles) + verified deltas: K staged by DMA,
// 2 barriers/tile (no mid barrier; Ps is per-wave), defer-max softmax in
// exp2 domain, per-lane l partials reduced once at epilogue.
// LDS: Ks 8K + Vt 10K + Ps 10K = 28 KB.
__global__ __launch_bounds__(256) void attn_k(const bf16* Q,
                                              const bf16* __restrict__ K,
                                              const bf16* __restrict__ V,
                                              bf16* Y) {
  const int t0 = blockIdx.x * 128;
  const int h  = blockIdx.y, bb = blockIdx.z, hk = h >> 1;
  const int tid = threadIdx.x, w = tid >> 6, lane = tid & 63;
  const int quad = lane >> 4, l16 = lane & 15;
  const int q0 = t0 + w * 32;

  __shared__ alignas(16) bf16 Ks[32*128];   // [key][128], seg-XOR swizzled
  __shared__ alignas(16) bf16 Vt[128*40];   // [d][key] transposed, +8 pad
  __shared__ alignas(16) bf16 Ps[4][32*40]; // per-wave P tile, stride 40

  bf16x8 qf[2][4];
  #pragma unroll
  for (int mt = 0; mt < 2; ++mt)
    #pragma unroll
    for (int kc = 0; kc < 4; ++kc)
      qf[mt][kc] = load8(Q + (size_t)(bb*T_ + q0 + mt*16 + l16)*C_ + h*D_ + kc*32 + quad*8);

  floatx4 o[2][8];
  #pragma unroll
  for (int mt = 0; mt < 2; ++mt)
    #pragma unroll
    for (int nt = 0; nt < 8; ++nt) o[mt][nt] = (floatx4){0.f, 0.f, 0.f, 0.f};
  float mr[2][4], lr[2][4];
  #pragma unroll
  for (int mt = 0; mt < 2; ++mt)
    #pragma unroll
    for (int r = 0; r < 4; ++r) { mr[mt][r] = -1.0e30f; lr[mt][r] = 0.f; }

  const int krow_in = lane >> 4;             // 0..3 (K staging row-in-group)
  const int kseg    = lane & 15;             // K staging LDS 16B seg

  const int kb0 = (t0 >= W_) ? (t0 - W_) : 0;
  for (int kb = kb0; kb < t0 + 128; kb += 32) {
    __syncthreads();
    // K: async DMA into seg-swizzled [key][128] (per-lane pre-swizzled source).
    // One gload covers 4 key rows (64 lanes x 16B); 8 groups of 4 rows.
    #pragma unroll
    for (int i = 0; i < 2; ++i) {
      const int g = w*2 + i;
      const int krow = g*4 + krow_in;
      const int gseg = (kseg & 8) | ((kseg ^ (krow & 7)) & 7);
      gload_lds16(K + (size_t)(bb*T_ + kb + krow)*(HK_*D_) + hk*D_ + gseg*8,
                  Ks + g*512);
    }
    // V: register transpose into Vt[d][col] (round-0 proven layout)
    #pragma unroll
    for (int jj = 0; jj < 2; ++jj) {
      const int idx = jj*256 + tid;          // 0..511
      const int key = idx >> 4, seg = idx & 15;
      union { bf16x8 v; bf16 hv[8]; } tmp;
      tmp.v = load8(V + (size_t)(bb*T_ + kb + key)*(HK_*D_) + hk*D_ + seg*8);
      const int col = (((key >> 3) ^ (seg & 3)) * 8) + (key & 7);
      #pragma unroll
      for (int e = 0; e < 8; ++e)
        Vt[(seg*8 + e)*40 + col] = tmp.hv[e];
    }
    __syncthreads();

    // QK^T: 8 MFMA over the 32-key tile
    floatx4 s[2][2];
    s[0][0] = (floatx4){0.f,0.f,0.f,0.f}; s[0][1] = (floatx4){0.f,0.f,0.f,0.f};
    s[1][0] = (floatx4){0.f,0.f,0.f,0.f}; s[1][1] = (floatx4){0.f,0.f,0.f,0.f};
    #pragma unroll
    for (int kc = 0; kc < 4; ++kc) {
      const int c8 = kc*4 + quad;
      const int s0 = (c8 & 8) | ((c8 ^ (l16 & 7)) & 7);
      bf16x8 bk0 = load8(Ks + l16*128 + s0*8);
      bf16x8 bk1 = load8(Ks + (16 + l16)*128 + s0*8);
      s[0][0] = mfma16(qf[0][kc], bk0, s[0][0]);
      s[0][1] = mfma16(qf[0][kc], bk1, s[0][1]);
      s[1][0] = mfma16(qf[1][kc], bk0, s[1][0]);
      s[1][1] = mfma16(qf[1][kc], bk1, s[1][1]);
    }

    // Online softmax in log2 domain; defer-max (T13, THR=8); per-lane l.
    const float scale2 = 0.12751744f;  // (1/sqrt(128)) * log2(e)
    #pragma unroll
    for (int mt = 0; mt < 2; ++mt)
      #pragma unroll
      for (int r = 0; r < 4; ++r) {
        const int qg  = q0 + mt*16 + quad*4 + r;
        const int kg0 = kb + l16, kg1 = kb + 16 + l16;
        const float sv0 = (kg0 <= qg && kg0 + W_ >= qg) ? s[mt][0][r]*scale2 : -3.0e38f;
        const float sv1 = (kg1 <= qg && kg1 + W_ >= qg) ? s[mt][1][r]*scale2 : -3.0e38f;
        float mx = fmaxf(sv0, sv1);
        #pragma unroll
        for (int off = 1; off < 16; off <<= 1) mx = fmaxf(mx, __shfl_xor(mx, off));
        // defer-max: skip O/l rescale unless some row's max grew by > 8 (log2)
        if (!__all(mx <= mr[mt][r] + 8.0f)) {
          const float mnew  = fmaxf(mr[mt][r], mx);
          const float alpha = exp2f(mr[mt][r] - mnew);
          mr[mt][r] = mnew;
          lr[mt][r] *= alpha;
          #pragma unroll
          for (int nt = 0; nt < 8; ++nt) o[mt][nt][r] *= alpha;
        }
        const float p0 = exp2f(sv0 - mr[mt][r]);
        const float p1 = exp2f(sv1 - mr[mt][r]);
        lr[mt][r] += p0 + p1;              // per-lane partial; reduced at epilogue
        const int prow = mt*16 + quad*4 + r;
        Ps[w][prow*40 + l16]      = __float2bfloat16(p0);
        Ps[w][prow*40 + 16 + l16] = __float2bfloat16(p1);
      }

    // PV: Ps is per-wave and LDS ops complete in order within a wave ->
    // no barrier needed (verified by round-2 pass).
    bf16x8 pa0 = load8(&Ps[w][l16*40 + quad*8]);
    bf16x8 pa1 = load8(&Ps[w][(16 + l16)*40 + quad*8]);
    #pragma unroll
    for (int nt = 0; nt < 8; ++nt) {
      const int d   = nt*16 + l16;
      const int blk = quad ^ ((d >> 3) & 3);
      bf16x8 bv = load8(Vt + d*40 + blk*8);
      o[0][nt] = mfma16(pa0, bv, o[0][nt]);
      o[1][nt] = mfma16(pa1, bv, o[1][nt]);
    }
  }

  #pragma unroll
  for (int mt = 0; mt < 2; ++mt)
    #pragma unroll
    for (int r = 0; r < 4; ++r) {
      float lt = lr[mt][r];
      #pragma unroll
      for (int off = 1; off < 16; off <<= 1) lt += __shfl_xor(lt, off);
      const float inv = 1.0f / lt;
      const size_t rowoff = (size_t)(bb*T_ + q0 + mt*16 + quad*4 + r) * C_ + h*D_;
      #pragma unroll
      for (int nt = 0; nt < 8; ++nt)
        Y[rowoff + nt*16 + l16] = __float2bfloat16(o[mt][nt][r] * inv);
    }
}

extern "C" void kernel_launch(void* const* d_in, const int* in_sizes, int n_in,
                              void* d_out, int out_size, void* d_ws, size_t ws_size,
                              hipStream_t stream) {
  (void)in_sizes; (void)n_in; (void)out_size; (void)ws_size;
  const float* x     = (const float*)d_in[0];
  const float* ve    = (const float*)d_in[1];
  const float* cosb  = (const float*)d_in[2];
  const float* sinb  = (const float*)d_in[3];
  const float* wq    = (const float*)d_in[4];
  const float* wk    = (const float*)d_in[5];
  const float* wv    = (const float*)d_in[6];
  const float* wproj = (const float*)d_in[7];
  const float* wgate = (const float*)d_in[8];

  // ws layout (75.5 MB): Q | Kw | Vw | wprojb
  bf16* Q      = (bf16*)d_ws;
  bf16* Kw     = Q  + (size_t)BT_ * C_;
  bf16* Vw     = Kw + (size_t)BT_ * (HK_*D_);
  bf16* wprojb = Vw + (size_t)BT_ * (HK_*D_);

  // Transient bf16 copies live INSIDE d_out (f32): dead before final GEMM.
  bf16* xb  = (bf16*)d_out;
  bf16* wqb = xb  + (size_t)BT_ * C_;
  bf16* wkb = wqb + (size_t)C_ * C_;
  bf16* wvb = wkb + (size_t)(HK_*D_) * C_;

  cvt_k<<<14336, 256, 0, stream>>>(x, wq, wk, wv, wproj, xb, wqb, wkb, wvb, wprojb);
  gemm_bt<bf16><<<dim3(C_/128,       BT_/128), 256, 0, stream>>>(xb, wqb, Q,  BT_, C_,     C_);
  gemm_bt<bf16><<<dim3((HK_*D_)/128, BT_/128), 256, 0, stream>>>(xb, wkb, Kw, BT_, HK_*D_, C_);
  gemm_bt<bf16><<<dim3((HK_*D_)/128, BT_/128), 256, 0, stream>>>(xb, wvb, Vw, BT_, HK_*D_, C_);
  fuse_k<<<dim3(BT_, 32), 128, 0, stream>>>(x, ve, cosb, sinb, wgate, Q, Kw, Vw);
  attn_k<<<dim3(T_/128, H_, B_), 256, 0, stream>>>(Q, Kw, Vw, Q /*Y in-place*/);
  gemm_bt<float><<<dim3(C_/128, BT_/128), 256, 0, stream>>>(Q, wprojb, (float*)d_out, BT_, C_, C_);
}

// Round 5
// 718.046 us; speedup vs baseline: 1.0796x; 1.0796x over previous
//
#include <hip/hip_runtime.h>
#include <hip/hip_bf16.h>
#include <cstdint>
#include <cstddef>

using bf16 = __hip_bfloat16;
typedef __bf16 bf16x8 __attribute__((ext_vector_type(8)));
typedef float floatx4 __attribute__((ext_vector_type(4)));

#define B_  2
#define T_  4096
#define C_  2048
#define H_  16
#define HK_ 8
#define D_  128
#define W_  512
#define BT_ (B_*T_)
#define QSTR 4096          // row stride of fused QKV buffer
#define KOFF 2048          // K column offset in QKV
#define VOFF 3072          // V column offset in QKV

__device__ __forceinline__ void gload_lds16(const void* g, void* l) {
  __builtin_amdgcn_global_load_lds((const __attribute__((address_space(1))) void*)g,
                                   (__attribute__((address_space(3))) void*)l, 16, 0, 0);
}
__device__ __forceinline__ floatx4 mfma16(bf16x8 a, bf16x8 b, floatx4 c) {
  return __builtin_amdgcn_mfma_f32_16x16x32_bf16(a, b, c, 0, 0, 0);
}
__device__ __forceinline__ __bf16 f2b(float f) {
  union { bf16 h; __bf16 b; } u; u.h = __float2bfloat16(f); return u.b;
}
__device__ __forceinline__ bf16x8 load8(const bf16* p) {
  return *(const bf16x8*)(const void*)p;
}
__device__ __forceinline__ bf16x8 load8(const float* p) {
  float4 a = *(const float4*)(const void*)p;
  float4 b = *(const float4*)(const void*)(p + 4);
  bf16x8 r;
  r[0]=f2b(a.x); r[1]=f2b(a.y); r[2]=f2b(a.z); r[3]=f2b(a.w);
  r[4]=f2b(b.x); r[5]=f2b(b.y); r[6]=f2b(b.z); r[7]=f2b(b.w);
  return r;
}
__device__ __forceinline__ void store1(float* p, float v) { *p = v; }
__device__ __forceinline__ void store1(bf16*  p, float v) { *p = __float2bfloat16(v); }

// One-shot f32 -> bf16 conversion of x and the four weight matrices.
// wq/wk/wv land contiguously -> one [4096, 2048] fused QKV weight.
__global__ __launch_bounds__(256) void cvt_k(const float* __restrict__ x,
                                             const float* __restrict__ wq,
                                             const float* __restrict__ wk,
                                             const float* __restrict__ wv,
                                             const float* __restrict__ wproj,
                                             bf16* __restrict__ xb,
                                             bf16* __restrict__ wqb,
                                             bf16* __restrict__ wkb,
                                             bf16* __restrict__ wvb,
                                             bf16* __restrict__ wprojb) {
  const int b = blockIdx.x;
  const float* src; bf16* dst; size_t off;
  if (b < 8192)       { src = x;     dst = xb;     off = (size_t)b * 2048; }
  else if (b < 10240) { src = wq;    dst = wqb;    off = (size_t)(b-8192) * 2048; }
  else if (b < 11264) { src = wk;    dst = wkb;    off = (size_t)(b-10240) * 2048; }
  else if (b < 12288) { src = wv;    dst = wvb;    off = (size_t)(b-11264) * 2048; }
  else                { src = wproj; dst = wprojb; off = (size_t)(b-12288) * 2048; }
  const size_t i = off + (size_t)threadIdx.x * 8;
  *(bf16x8*)(void*)(dst + i) = load8(src + i);
}

// C[m][n] = sum_k A[m][k] * B[n][k], all-bf16 inputs, m97-style DMA staging.
// A row stride lda, B row stride Kd, C row stride ldc.
template<typename TC>
__global__ __launch_bounds__(256) void gemm_bt(const bf16* __restrict__ A,
                                               const bf16* __restrict__ Bw,
                                               TC* __restrict__ Cc,
                                               int M, int N, int Kd,
                                               int lda, int ldc) {
  __shared__ alignas(16) bf16 As[128*64];
  __shared__ alignas(16) bf16 Bs[128*64];
  const int tid = threadIdx.x;
  const int w = tid >> 6, lane = tid & 63;
  const int quad = lane >> 4, l16 = lane & 15;
  const int wm = (w & 1) * 64, wn = (w >> 1) * 64;
  const int m0 = blockIdx.y * 128, n0 = blockIdx.x * 128;
  const int srow = lane >> 3, sseg = lane & 7;

  floatx4 acc[4][4];
  #pragma unroll
  for (int i = 0; i < 4; ++i)
    #pragma unroll
    for (int j = 0; j < 4; ++j) acc[i][j] = (floatx4){0.f, 0.f, 0.f, 0.f};

  for (int k0 = 0; k0 < Kd; k0 += 64) {
    __syncthreads();
    #pragma unroll
    for (int i = 0; i < 4; ++i) {
      const int r  = w*32 + i*8 + srow;
      const int gs = (sseg ^ (r & 7)) * 8;
      gload_lds16(A  + (size_t)(m0 + r)*lda + k0 + gs, As + (w*32 + i*8)*64);
      gload_lds16(Bw + (size_t)(n0 + r)*Kd  + k0 + gs, Bs + (w*32 + i*8)*64);
    }
    __syncthreads();
    #pragma unroll
    for (int kk = 0; kk < 2; ++kk) {
      bf16x8 af[4], bfr[4];
      #pragma unroll
      for (int mt = 0; mt < 4; ++mt) {
        const int m = wm + mt*16 + l16;
        af[mt] = load8(As + m*64 + (((kk*4 + quad) ^ (m & 7)) * 8));
      }
      #pragma unroll
      for (int nt = 0; nt < 4; ++nt) {
        const int n = wn + nt*16 + l16;
        bfr[nt] = load8(Bs + n*64 + (((kk*4 + quad) ^ (n & 7)) * 8));
      }
      #pragma unroll
      for (int mt = 0; mt < 4; ++mt)
        #pragma unroll
        for (int nt = 0; nt < 4; ++nt)
          acc[mt][nt] = mfma16(af[mt], bfr[nt], acc[mt][nt]);
    }
  }

  #pragma unroll
  for (int mt = 0; mt < 4; ++mt)
    #pragma unroll
    for (int r = 0; r < 4; ++r) {
      const size_t row = (size_t)(m0 + wm + mt*16 + quad*4 + r);
      #pragma unroll
      for (int nt = 0; nt < 4; ++nt) {
        const int col = n0 + wn + nt*16 + l16;
        store1(Cc + row*ldc + col, acc[mt][nt][r]);
      }
    }
}

// grid (BT, 32), block 128. Operates in-place on fused QKV [BT, 4096].
__global__ __launch_bounds__(128) void fuse_k(const float* __restrict__ x,
                                              const float* __restrict__ ve,
                                              const float* __restrict__ cosb,
                                              const float* __restrict__ sinb,
                                              const float* __restrict__ wgate,
                                              bf16* __restrict__ QKV) {
  const int tok = blockIdx.x;
  const int j   = blockIdx.y;
  const int t   = tok & (T_ - 1);
  const int tid = threadIdx.x;

  if (j < 24) {
    bf16* base = QKV + (size_t)tok * QSTR
               + ((j < 16) ? j * D_ : (KOFF + (j - 16) * D_));
    const int d  = tid;
    const float v0 = __bfloat162float(base[d]);
    const float vp = __bfloat162float(base[d ^ 64]);
    const int dd = d & 63;
    const float c = cosb[t*64 + dd];
    const float s = sinb[t*64 + dd];
    const float val = (d < 64) ? (v0*c + vp*s) : (v0*c - vp*s);
    float ss = val * val;
    #pragma unroll
    for (int off = 1; off < 64; off <<= 1) ss += __shfl_xor(ss, off);
    __shared__ float red[2];
    if ((tid & 63) == 0) red[tid >> 6] = ss;
    __syncthreads();
    const float tot = red[0] + red[1];
    const float sc = rsqrtf(tot * (1.0f/128.0f) + 1.1920929e-7f);
    base[d] = __float2bfloat16(val * sc);
  } else {
    const int hk = j - 24;
    float z = 0.f;
    #pragma unroll
    for (int c = 0; c < 32; ++c)
      z += x[(size_t)tok * C_ + c] * wgate[hk*32 + c];
    const float gate = 2.0f / (1.0f + __expf(-z));
    const size_t vidx  = (size_t)tok * QSTR + VOFF + hk * D_ + tid;
    const size_t veidx = (size_t)tok * (HK_*D_) + hk * D_ + tid;
    QKV[vidx] = __float2bfloat16(__bfloat162float(QKV[vidx]) + gate * ve[veidx]);
  }
}

// Flash-style windowed attention on fused QKV [BT,4096]. grid (T/128, H, B),
// block 256 (4 waves). 32-key tiles, K staged by DMA, 2 barriers/tile,
// defer-max softmax in exp2 domain, per-lane l partials.
// Y written in-place over the Q columns (cols < 2048); K/V reads are cols
// >= 2048, and each block reads only its own Q rows before writing them.
// LDS: Ks 8K + Vt 10K + Ps 10K = 28 KB. launch_bounds(,4) caps VGPR at 128
// (round-4 lesson: 136 VGPR -> 3 waves/SIMD -> 1.65x slowdown).
__global__ __launch_bounds__(256, 4) void attn_k(bf16* QKV) {
  const int t0 = blockIdx.x * 128;
  const int h  = blockIdx.y, bb = blockIdx.z, hk = h >> 1;
  const int tid = threadIdx.x, w = tid >> 6, lane = tid & 63;
  const int quad = lane >> 4, l16 = lane & 15;
  const int q0 = t0 + w * 32;

  __shared__ alignas(16) bf16 Ks[32*128];   // [key][128], seg-XOR swizzled
  __shared__ alignas(16) bf16 Vt[128*40];   // [d][key] transposed, +8 pad
  __shared__ alignas(16) bf16 Ps[4][32*40]; // per-wave P tile, stride 40

  bf16x8 qf[2][4];
  #pragma unroll
  for (int mt = 0; mt < 2; ++mt)
    #pragma unroll
    for (int kc = 0; kc < 4; ++kc)
      qf[mt][kc] = load8(QKV + (size_t)(bb*T_ + q0 + mt*16 + l16)*QSTR + h*D_ + kc*32 + quad*8);

  floatx4 o[2][8];
  #pragma unroll
  for (int mt = 0; mt < 2; ++mt)
    #pragma unroll
    for (int nt = 0; nt < 8; ++nt) o[mt][nt] = (floatx4){0.f, 0.f, 0.f, 0.f};
  float mr[2][4], lr[2][4];
  #pragma unroll
  for (int mt = 0; mt < 2; ++mt)
    #pragma unroll
    for (int r = 0; r < 4; ++r) { mr[mt][r] = -1.0e30f; lr[mt][r] = 0.f; }

  const int krow_in = lane >> 4;             // 0..3 (K staging row-in-group)
  const int kseg    = lane & 15;             // K staging LDS 16B seg

  const int kb0 = (t0 >= W_) ? (t0 - W_) : 0;
  for (int kb = kb0; kb < t0 + 128; kb += 32) {
    __syncthreads();
    // K: async DMA into seg-swizzled [key][128] (per-lane pre-swizzled source).
    #pragma unroll
    for (int i = 0; i < 2; ++i) {
      const int g = w*2 + i;
      const int krow = g*4 + krow_in;
      const int gseg = (kseg & 8) | ((kseg ^ (krow & 7)) & 7);
      gload_lds16(QKV + (size_t)(bb*T_ + kb + krow)*QSTR + KOFF + hk*D_ + gseg*8,
                  Ks + g*512);
    }
    // V: register transpose into Vt[d][col] (round-0 proven layout)
    #pragma unroll
    for (int jj = 0; jj < 2; ++jj) {
      const int idx = jj*256 + tid;          // 0..511
      const int key = idx >> 4, seg = idx & 15;
      union { bf16x8 v; bf16 hv[8]; } tmp;
      tmp.v = load8(QKV + (size_t)(bb*T_ + kb + key)*QSTR + VOFF + hk*D_ + seg*8);
      const int col = (((key >> 3) ^ (seg & 3)) * 8) + (key & 7);
      #pragma unroll
      for (int e = 0; e < 8; ++e)
        Vt[(seg*8 + e)*40 + col] = tmp.hv[e];
    }
    __syncthreads();

    // QK^T: 8 MFMA over the 32-key tile
    floatx4 s[2][2];
    s[0][0] = (floatx4){0.f,0.f,0.f,0.f}; s[0][1] = (floatx4){0.f,0.f,0.f,0.f};
    s[1][0] = (floatx4){0.f,0.f,0.f,0.f}; s[1][1] = (floatx4){0.f,0.f,0.f,0.f};
    #pragma unroll
    for (int kc = 0; kc < 4; ++kc) {
      const int c8 = kc*4 + quad;
      const int s0 = (c8 & 8) | ((c8 ^ (l16 & 7)) & 7);
      bf16x8 bk0 = load8(Ks + l16*128 + s0*8);
      bf16x8 bk1 = load8(Ks + (16 + l16)*128 + s0*8);
      s[0][0] = mfma16(qf[0][kc], bk0, s[0][0]);
      s[0][1] = mfma16(qf[0][kc], bk1, s[0][1]);
      s[1][0] = mfma16(qf[1][kc], bk0, s[1][0]);
      s[1][1] = mfma16(qf[1][kc], bk1, s[1][1]);
    }

    // Online softmax in log2 domain; defer-max (T13, THR=8); per-lane l.
    const float scale2 = 0.12751744f;  // (1/sqrt(128)) * log2(e)
    #pragma unroll
    for (int mt = 0; mt < 2; ++mt)
      #pragma unroll
      for (int r = 0; r < 4; ++r) {
        const int qg  = q0 + mt*16 + quad*4 + r;
        const int kg0 = kb + l16, kg1 = kb + 16 + l16;
        const float sv0 = (kg0 <= qg && kg0 + W_ >= qg) ? s[mt][0][r]*scale2 : -3.0e38f;
        const float sv1 = (kg1 <= qg && kg1 + W_ >= qg) ? s[mt][1][r]*scale2 : -3.0e38f;
        float mx = fmaxf(sv0, sv1);
        #pragma unroll
        for (int off = 1; off < 16; off <<= 1) mx = fmaxf(mx, __shfl_xor(mx, off));
        // defer-max: skip O/l rescale unless some row's max grew by > 8 (log2)
        if (!__all(mx <= mr[mt][r] + 8.0f)) {
          const float mnew  = fmaxf(mr[mt][r], mx);
          const float alpha = exp2f(mr[mt][r] - mnew);
          mr[mt][r] = mnew;
          lr[mt][r] *= alpha;
          #pragma unroll
          for (int nt = 0; nt < 8; ++nt) o[mt][nt][r] *= alpha;
        }
        const float p0 = exp2f(sv0 - mr[mt][r]);
        const float p1 = exp2f(sv1 - mr[mt][r]);
        lr[mt][r] += p0 + p1;              // per-lane partial; reduced at epilogue
        const int prow = mt*16 + quad*4 + r;
        Ps[w][prow*40 + l16]      = __float2bfloat16(p0);
        Ps[w][prow*40 + 16 + l16] = __float2bfloat16(p1);
      }

    // PV: Ps is per-wave and LDS ops complete in order within a wave ->
    // no barrier needed (verified by round-2 pass).
    bf16x8 pa0 = load8(&Ps[w][l16*40 + quad*8]);
    bf16x8 pa1 = load8(&Ps[w][(16 + l16)*40 + quad*8]);
    #pragma unroll
    for (int nt = 0; nt < 8; ++nt) {
      const int d   = nt*16 + l16;
      const int blk = quad ^ ((d >> 3) & 3);
      bf16x8 bv = load8(Vt + d*40 + blk*8);
      o[0][nt] = mfma16(pa0, bv, o[0][nt]);
      o[1][nt] = mfma16(pa1, bv, o[1][nt]);
    }
  }

  #pragma unroll
  for (int mt = 0; mt < 2; ++mt)
    #pragma unroll
    for (int r = 0; r < 4; ++r) {
      float lt = lr[mt][r];
      #pragma unroll
      for (int off = 1; off < 16; off <<= 1) lt += __shfl_xor(lt, off);
      const float inv = 1.0f / lt;
      const size_t rowoff = (size_t)(bb*T_ + q0 + mt*16 + quad*4 + r) * QSTR + h*D_;
      #pragma unroll
      for (int nt = 0; nt < 8; ++nt)
        QKV[rowoff + nt*16 + l16] = __float2bfloat16(o[mt][nt][r] * inv);
    }
}

extern "C" void kernel_launch(void* const* d_in, const int* in_sizes, int n_in,
                              void* d_out, int out_size, void* d_ws, size_t ws_size,
                              hipStream_t stream) {
  (void)in_sizes; (void)n_in; (void)out_size; (void)ws_size;
  const float* x     = (const float*)d_in[0];
  const float* ve    = (const float*)d_in[1];
  const float* cosb  = (const float*)d_in[2];
  const float* sinb  = (const float*)d_in[3];
  const float* wq    = (const float*)d_in[4];
  const float* wk    = (const float*)d_in[5];
  const float* wv    = (const float*)d_in[6];
  const float* wproj = (const float*)d_in[7];
  const float* wgate = (const float*)d_in[8];

  // ws layout (75.5 MB): QKV [BT,4096] | wprojb [2048,2048]
  bf16* QKV    = (bf16*)d_ws;
  bf16* wprojb = QKV + (size_t)BT_ * QSTR;

  // Transient bf16 copies live INSIDE d_out (f32): dead before final GEMM.
  // wq|wk|wv rows are contiguous -> fused [4096,2048] QKV weight.
  bf16* xb    = (bf16*)d_out;
  bf16* wqkvb = xb  + (size_t)BT_ * C_;
  bf16* wqb   = wqkvb;
  bf16* wkb   = wqb + (size_t)C_ * C_;
  bf16* wvb   = wkb + (size_t)(HK_*D_) * C_;

  cvt_k<<<14336, 256, 0, stream>>>(x, wq, wk, wv, wproj, xb, wqb, wkb, wvb, wprojb);
  gemm_bt<bf16><<<dim3(QSTR/128, BT_/128), 256, 0, stream>>>(xb, wqkvb, QKV,
                                                             BT_, QSTR, C_, C_, QSTR);
  fuse_k<<<dim3(BT_, 32), 128, 0, stream>>>(x, ve, cosb, sinb, wgate, QKV);
  attn_k<<<dim3(T_/128, H_, B_), 256, 0, stream>>>(QKV);
  gemm_bt<float><<<dim3(C_/128, BT_/128), 256, 0, stream>>>(QKV, wprojb, (float*)d_out,
                                                            BT_, C_, C_, QSTR, C_);
}

// Round 6
// 617.483 us; speedup vs baseline: 1.2554x; 1.1629x over previous
//
#include <hip/hip_runtime.h>
#include <hip/hip_bf16.h>
#include <cstdint>
#include <cstddef>

using bf16 = __hip_bfloat16;
typedef __bf16 bf16x8 __attribute__((ext_vector_type(8)));
typedef float floatx4 __attribute__((ext_vector_type(4)));

#define B_  2
#define T_  4096
#define C_  2048
#define H_  16
#define HK_ 8
#define D_  128
#define W_  512
#define BT_ (B_*T_)
#define QSTR 4096          // row stride of fused QKV buffer
#define KOFF 2048          // K column offset in QKV
#define VOFF 3072          // V column offset in QKV

__device__ __forceinline__ void gload_lds16(const void* g, void* l) {
  __builtin_amdgcn_global_load_lds((const __attribute__((address_space(1))) void*)g,
                                   (__attribute__((address_space(3))) void*)l, 16, 0, 0);
}
__device__ __forceinline__ floatx4 mfma16(bf16x8 a, bf16x8 b, floatx4 c) {
  return __builtin_amdgcn_mfma_f32_16x16x32_bf16(a, b, c, 0, 0, 0);
}
__device__ __forceinline__ __bf16 f2b(float f) {
  union { bf16 h; __bf16 b; } u; u.h = __float2bfloat16(f); return u.b;
}
__device__ __forceinline__ bf16x8 load8(const bf16* p) {
  return *(const bf16x8*)(const void*)p;
}
__device__ __forceinline__ bf16x8 load8(const float* p) {
  float4 a = *(const float4*)(const void*)p;
  float4 b = *(const float4*)(const void*)(p + 4);
  bf16x8 r;
  r[0]=f2b(a.x); r[1]=f2b(a.y); r[2]=f2b(a.z); r[3]=f2b(a.w);
  r[4]=f2b(b.x); r[5]=f2b(b.y); r[6]=f2b(b.z); r[7]=f2b(b.w);
  return r;
}
__device__ __forceinline__ void store1(float* p, float v) { *p = v; }
__device__ __forceinline__ void store1(bf16*  p, float v) { *p = __float2bfloat16(v); }

// One-shot f32 -> bf16 conversion of x and the four weight matrices.
// wq/wk/wv land contiguously -> one [4096, 2048] fused QKV weight.
__global__ __launch_bounds__(256) void cvt_k(const float* __restrict__ x,
                                             const float* __restrict__ wq,
                                             const float* __restrict__ wk,
                                             const float* __restrict__ wv,
                                             const float* __restrict__ wproj,
                                             bf16* __restrict__ xb,
                                             bf16* __restrict__ wqb,
                                             bf16* __restrict__ wkb,
                                             bf16* __restrict__ wvb,
                                             bf16* __restrict__ wprojb) {
  const int b = blockIdx.x;
  const float* src; bf16* dst; size_t off;
  if (b < 8192)       { src = x;     dst = xb;     off = (size_t)b * 2048; }
  else if (b < 10240) { src = wq;    dst = wqb;    off = (size_t)(b-8192) * 2048; }
  else if (b < 11264) { src = wk;    dst = wkb;    off = (size_t)(b-10240) * 2048; }
  else if (b < 12288) { src = wv;    dst = wvb;    off = (size_t)(b-11264) * 2048; }
  else                { src = wproj; dst = wprojb; off = (size_t)(b-12288) * 2048; }
  const size_t i = off + (size_t)threadIdx.x * 8;
  *(bf16x8*)(void*)(dst + i) = load8(src + i);
}

// C[m][n] = sum_k A[m][k] * B[n][k], all-bf16 inputs, m97-style DMA staging.
// A row stride lda, B row stride Kd, C row stride ldc.
template<typename TC>
__global__ __launch_bounds__(256) void gemm_bt(const bf16* __restrict__ A,
                                               const bf16* __restrict__ Bw,
                                               TC* __restrict__ Cc,
                                               int M, int N, int Kd,
                                               int lda, int ldc) {
  __shared__ alignas(16) bf16 As[128*64];
  __shared__ alignas(16) bf16 Bs[128*64];
  const int tid = threadIdx.x;
  const int w = tid >> 6, lane = tid & 63;
  const int quad = lane >> 4, l16 = lane & 15;
  const int wm = (w & 1) * 64, wn = (w >> 1) * 64;
  const int m0 = blockIdx.y * 128, n0 = blockIdx.x * 128;
  const int srow = lane >> 3, sseg = lane & 7;

  floatx4 acc[4][4];
  #pragma unroll
  for (int i = 0; i < 4; ++i)
    #pragma unroll
    for (int j = 0; j < 4; ++j) acc[i][j] = (floatx4){0.f, 0.f, 0.f, 0.f};

  for (int k0 = 0; k0 < Kd; k0 += 64) {
    __syncthreads();
    #pragma unroll
    for (int i = 0; i < 4; ++i) {
      const int r  = w*32 + i*8 + srow;
      const int gs = (sseg ^ (r & 7)) * 8;
      gload_lds16(A  + (size_t)(m0 + r)*lda + k0 + gs, As + (w*32 + i*8)*64);
      gload_lds16(Bw + (size_t)(n0 + r)*Kd  + k0 + gs, Bs + (w*32 + i*8)*64);
    }
    __syncthreads();
    #pragma unroll
    for (int kk = 0; kk < 2; ++kk) {
      bf16x8 af[4], bfr[4];
      #pragma unroll
      for (int mt = 0; mt < 4; ++mt) {
        const int m = wm + mt*16 + l16;
        af[mt] = load8(As + m*64 + (((kk*4 + quad) ^ (m & 7)) * 8));
      }
      #pragma unroll
      for (int nt = 0; nt < 4; ++nt) {
        const int n = wn + nt*16 + l16;
        bfr[nt] = load8(Bs + n*64 + (((kk*4 + quad) ^ (n & 7)) * 8));
      }
      #pragma unroll
      for (int mt = 0; mt < 4; ++mt)
        #pragma unroll
        for (int nt = 0; nt < 4; ++nt)
          acc[mt][nt] = mfma16(af[mt], bfr[nt], acc[mt][nt]);
    }
  }

  #pragma unroll
  for (int mt = 0; mt < 4; ++mt)
    #pragma unroll
    for (int r = 0; r < 4; ++r) {
      const size_t row = (size_t)(m0 + wm + mt*16 + quad*4 + r);
      #pragma unroll
      for (int nt = 0; nt < 4; ++nt) {
        const int col = n0 + wn + nt*16 + l16;
        store1(Cc + row*ldc + col, acc[mt][nt][r]);
      }
    }
}

// grid (BT, 32), block 128. Operates in-place on fused QKV [BT, 4096].
__global__ __launch_bounds__(128) void fuse_k(const float* __restrict__ x,
                                              const float* __restrict__ ve,
                                              const float* __restrict__ cosb,
                                              const float* __restrict__ sinb,
                                              const float* __restrict__ wgate,
                                              bf16* __restrict__ QKV) {
  const int tok = blockIdx.x;
  const int j   = blockIdx.y;
  const int t   = tok & (T_ - 1);
  const int tid = threadIdx.x;

  if (j < 24) {
    bf16* base = QKV + (size_t)tok * QSTR
               + ((j < 16) ? j * D_ : (KOFF + (j - 16) * D_));
    const int d  = tid;
    const float v0 = __bfloat162float(base[d]);
    const float vp = __bfloat162float(base[d ^ 64]);
    const int dd = d & 63;
    const float c = cosb[t*64 + dd];
    const float s = sinb[t*64 + dd];
    const float val = (d < 64) ? (v0*c + vp*s) : (v0*c - vp*s);
    float ss = val * val;
    #pragma unroll
    for (int off = 1; off < 64; off <<= 1) ss += __shfl_xor(ss, off);
    __shared__ float red[2];
    if ((tid & 63) == 0) red[tid >> 6] = ss;
    __syncthreads();
    const float tot = red[0] + red[1];
    const float sc = rsqrtf(tot * (1.0f/128.0f) + 1.1920929e-7f);
    base[d] = __float2bfloat16(val * sc);
  } else {
    const int hk = j - 24;
    float z = 0.f;
    #pragma unroll
    for (int c = 0; c < 32; ++c)
      z += x[(size_t)tok * C_ + c] * wgate[hk*32 + c];
    const float gate = 2.0f / (1.0f + __expf(-z));
    const size_t vidx  = (size_t)tok * QSTR + VOFF + hk * D_ + tid;
    const size_t veidx = (size_t)tok * (HK_*D_) + hk * D_ + tid;
    QKV[vidx] = __float2bfloat16(__bfloat162float(QKV[vidx]) + gate * ve[veidx]);
  }
}

// Flash-style windowed attention on fused QKV [BT,4096]. grid (T/128, H, B),
// block 256 (4 waves). Round-0 structure: 32-key tiles, 3 barriers/tile
// (the pre-PV barrier doubles as a register-pressure fence: removing it
// pushed VGPR 124->136 -> occupancy cliff, round 4), unconditional online-
// softmax rescale (defer-max bookkeeping also costs registers).
// Register-neutral upgrades kept: K staged by DMA (global_load_lds),
// exp2-domain softmax, per-lane l partials reduced once at epilogue.
// NO launch_bounds min-waves arg (round 5: forcing 4 blocks/CU spilled the
// 64-reg accumulator to scratch -> 6x HBM traffic).
// LDS: Ks 8K + Vt 10K + Ps 10K = 28 KB.
__global__ __launch_bounds__(256) void attn_k(bf16* QKV) {
  const int t0 = blockIdx.x * 128;
  const int h  = blockIdx.y, bb = blockIdx.z, hk = h >> 1;
  const int tid = threadIdx.x, w = tid >> 6, lane = tid & 63;
  const int quad = lane >> 4, l16 = lane & 15;
  const int q0 = t0 + w * 32;

  __shared__ alignas(16) bf16 Ks[32*128];   // [key][128], seg-XOR swizzled
  __shared__ alignas(16) bf16 Vt[128*40];   // [d][key] transposed, +8 pad
  __shared__ alignas(16) bf16 Ps[4][32*40]; // per-wave P tile, stride 40

  bf16x8 qf[2][4];
  #pragma unroll
  for (int mt = 0; mt < 2; ++mt)
    #pragma unroll
    for (int kc = 0; kc < 4; ++kc)
      qf[mt][kc] = load8(QKV + (size_t)(bb*T_ + q0 + mt*16 + l16)*QSTR + h*D_ + kc*32 + quad*8);

  floatx4 o[2][8];
  #pragma unroll
  for (int mt = 0; mt < 2; ++mt)
    #pragma unroll
    for (int nt = 0; nt < 8; ++nt) o[mt][nt] = (floatx4){0.f, 0.f, 0.f, 0.f};
  float mr[2][4], lr[2][4];
  #pragma unroll
  for (int mt = 0; mt < 2; ++mt)
    #pragma unroll
    for (int r = 0; r < 4; ++r) { mr[mt][r] = -1.0e30f; lr[mt][r] = 0.f; }

  const int krow_in = lane >> 4;             // 0..3 (K staging row-in-group)
  const int kseg    = lane & 15;             // K staging LDS 16B seg

  const int kb0 = (t0 >= W_) ? (t0 - W_) : 0;
  for (int kb = kb0; kb < t0 + 128; kb += 32) {
    __syncthreads();
    // K: async DMA into seg-swizzled [key][128] (per-lane pre-swizzled source).
    #pragma unroll
    for (int i = 0; i < 2; ++i) {
      const int g = w*2 + i;
      const int krow = g*4 + krow_in;
      const int gseg = (kseg & 8) | ((kseg ^ (krow & 7)) & 7);
      gload_lds16(QKV + (size_t)(bb*T_ + kb + krow)*QSTR + KOFF + hk*D_ + gseg*8,
                  Ks + g*512);
    }
    // V: register transpose into Vt[d][col] (round-0 proven layout)
    #pragma unroll
    for (int jj = 0; jj < 2; ++jj) {
      const int idx = jj*256 + tid;          // 0..511
      const int key = idx >> 4, seg = idx & 15;
      union { bf16x8 v; bf16 hv[8]; } tmp;
      tmp.v = load8(QKV + (size_t)(bb*T_ + kb + key)*QSTR + VOFF + hk*D_ + seg*8);
      const int col = (((key >> 3) ^ (seg & 3)) * 8) + (key & 7);
      #pragma unroll
      for (int e = 0; e < 8; ++e)
        Vt[(seg*8 + e)*40 + col] = tmp.hv[e];
    }
    __syncthreads();

    // QK^T: 8 MFMA over the 32-key tile
    floatx4 s[2][2];
    s[0][0] = (floatx4){0.f,0.f,0.f,0.f}; s[0][1] = (floatx4){0.f,0.f,0.f,0.f};
    s[1][0] = (floatx4){0.f,0.f,0.f,0.f}; s[1][1] = (floatx4){0.f,0.f,0.f,0.f};
    #pragma unroll
    for (int kc = 0; kc < 4; ++kc) {
      const int c8 = kc*4 + quad;
      const int s0 = (c8 & 8) | ((c8 ^ (l16 & 7)) & 7);
      bf16x8 bk0 = load8(Ks + l16*128 + s0*8);
      bf16x8 bk1 = load8(Ks + (16 + l16)*128 + s0*8);
      s[0][0] = mfma16(qf[0][kc], bk0, s[0][0]);
      s[0][1] = mfma16(qf[0][kc], bk1, s[0][1]);
      s[1][0] = mfma16(qf[1][kc], bk0, s[1][0]);
      s[1][1] = mfma16(qf[1][kc], bk1, s[1][1]);
    }

    // Online softmax in log2 domain (unconditional rescale, round-0 style);
    // per-lane l partials (no in-loop reduce).
    const float scale2 = 0.12751744f;  // (1/sqrt(128)) * log2(e)
    #pragma unroll
    for (int mt = 0; mt < 2; ++mt)
      #pragma unroll
      for (int r = 0; r < 4; ++r) {
        const int qg  = q0 + mt*16 + quad*4 + r;
        const int kg0 = kb + l16, kg1 = kb + 16 + l16;
        const float sv0 = (kg0 <= qg && kg0 + W_ >= qg) ? s[mt][0][r]*scale2 : -3.0e38f;
        const float sv1 = (kg1 <= qg && kg1 + W_ >= qg) ? s[mt][1][r]*scale2 : -3.0e38f;
        float mx = fmaxf(sv0, sv1);
        #pragma unroll
        for (int off = 1; off < 16; off <<= 1) mx = fmaxf(mx, __shfl_xor(mx, off));
        const float mnew  = fmaxf(mr[mt][r], mx);
        const float alpha = exp2f(mr[mt][r] - mnew);
        mr[mt][r] = mnew;
        const float p0 = exp2f(sv0 - mnew);
        const float p1 = exp2f(sv1 - mnew);
        lr[mt][r] = lr[mt][r] * alpha + p0 + p1;  // per-lane partial
        const int prow = mt*16 + quad*4 + r;
        Ps[w][prow*40 + l16]      = __float2bfloat16(p0);
        Ps[w][prow*40 + 16 + l16] = __float2bfloat16(p1);
        #pragma unroll
        for (int nt = 0; nt < 8; ++nt) o[mt][nt][r] *= alpha;
      }

    __syncthreads();   // round-0 pre-PV barrier: scheduling/register fence

    bf16x8 pa0 = load8(&Ps[w][l16*40 + quad*8]);
    bf16x8 pa1 = load8(&Ps[w][(16 + l16)*40 + quad*8]);
    #pragma unroll
    for (int nt = 0; nt < 8; ++nt) {
      const int d   = nt*16 + l16;
      const int blk = quad ^ ((d >> 3) & 3);
      bf16x8 bv = load8(Vt + d*40 + blk*8);
      o[0][nt] = mfma16(pa0, bv, o[0][nt]);
      o[1][nt] = mfma16(pa1, bv, o[1][nt]);
    }
  }

  #pragma unroll
  for (int mt = 0; mt < 2; ++mt)
    #pragma unroll
    for (int r = 0; r < 4; ++r) {
      float lt = lr[mt][r];
      #pragma unroll
      for (int off = 1; off < 16; off <<= 1) lt += __shfl_xor(lt, off);
      const float inv = 1.0f / lt;
      const size_t rowoff = (size_t)(bb*T_ + q0 + mt*16 + quad*4 + r) * QSTR + h*D_;
      #pragma unroll
      for (int nt = 0; nt < 8; ++nt)
        QKV[rowoff + nt*16 + l16] = __float2bfloat16(o[mt][nt][r] * inv);
    }
}

extern "C" void kernel_launch(void* const* d_in, const int* in_sizes, int n_in,
                              void* d_out, int out_size, void* d_ws, size_t ws_size,
                              hipStream_t stream) {
  (void)in_sizes; (void)n_in; (void)out_size; (void)ws_size;
  const float* x     = (const float*)d_in[0];
  const float* ve    = (const float*)d_in[1];
  const float* cosb  = (const float*)d_in[2];
  const float* sinb  = (const float*)d_in[3];
  const float* wq    = (const float*)d_in[4];
  const float* wk    = (const float*)d_in[5];
  const float* wv    = (const float*)d_in[6];
  const float* wproj = (const float*)d_in[7];
  const float* wgate = (const float*)d_in[8];

  // ws layout (75.5 MB): QKV [BT,4096] | wprojb [2048,2048]
  bf16* QKV    = (bf16*)d_ws;
  bf16* wprojb = QKV + (size_t)BT_ * QSTR;

  // Transient bf16 copies live INSIDE d_out (f32): dead before final GEMM.
  // wq|wk|wv rows are contiguous -> fused [4096,2048] QKV weight.
  bf16* xb    = (bf16*)d_out;
  bf16* wqkvb = xb  + (size_t)BT_ * C_;
  bf16* wqb   = wqkvb;
  bf16* wkb   = wqb + (size_t)C_ * C_;
  bf16* wvb   = wkb + (size_t)(HK_*D_) * C_;

  cvt_k<<<14336, 256, 0, stream>>>(x, wq, wk, wv, wproj, xb, wqb, wkb, wvb, wprojb);
  gemm_bt<bf16><<<dim3(QSTR/128, BT_/128), 256, 0, stream>>>(xb, wqkvb, QKV,
                                                             BT_, QSTR, C_, C_, QSTR);
  fuse_k<<<dim3(BT_, 32), 128, 0, stream>>>(x, ve, cosb, sinb, wgate, QKV);
  attn_k<<<dim3(T_/128, H_, B_), 256, 0, stream>>>(QKV);
  gemm_bt<float><<<dim3(C_/128, BT_/128), 256, 0, stream>>>(QKV, wprojb, (float*)d_out,
                                                            BT_, C_, C_, QSTR, C_);
}

// Round 7
// 563.542 us; speedup vs baseline: 1.3755x; 1.0957x over previous
//
#include <hip/hip_runtime.h>
#include <hip/hip_bf16.h>
#include <cstdint>
#include <cstddef>

using bf16 = __hip_bfloat16;
typedef __bf16 bf16x8 __attribute__((ext_vector_type(8)));
typedef float floatx4 __attribute__((ext_vector_type(4)));

#define B_  2
#define T_  4096
#define C_  2048
#define H_  16
#define HK_ 8
#define D_  128
#define W_  512
#define BT_ (B_*T_)
#define QSTR 4096          // row stride of fused QKV buffer
#define KOFF 2048          // K column offset in QKV
#define VOFF 3072          // V column offset in QKV

__device__ __forceinline__ void gload_lds16(const void* g, void* l) {
  __builtin_amdgcn_global_load_lds((const __attribute__((address_space(1))) void*)g,
                                   (__attribute__((address_space(3))) void*)l, 16, 0, 0);
}
__device__ __forceinline__ floatx4 mfma16(bf16x8 a, bf16x8 b, floatx4 c) {
  return __builtin_amdgcn_mfma_f32_16x16x32_bf16(a, b, c, 0, 0, 0);
}
__device__ __forceinline__ __bf16 f2b(float f) {
  union { bf16 h; __bf16 b; } u; u.h = __float2bfloat16(f); return u.b;
}
__device__ __forceinline__ bf16x8 load8(const bf16* p) {
  return *(const bf16x8*)(const void*)p;
}
__device__ __forceinline__ bf16x8 load8(const float* p) {
  float4 a = *(const float4*)(const void*)p;
  float4 b = *(const float4*)(const void*)(p + 4);
  bf16x8 r;
  r[0]=f2b(a.x); r[1]=f2b(a.y); r[2]=f2b(a.z); r[3]=f2b(a.w);
  r[4]=f2b(b.x); r[5]=f2b(b.y); r[6]=f2b(b.z); r[7]=f2b(b.w);
  return r;
}
__device__ __forceinline__ void store1(float* p, float v) { *p = v; }
__device__ __forceinline__ void store1(bf16*  p, float v) { *p = __float2bfloat16(v); }

// One-shot f32 -> bf16 conversion of x and the four weight matrices.
// wq/wk/wv land contiguously -> one [4096, 2048] fused QKV weight.
__global__ __launch_bounds__(256) void cvt_k(const float* __restrict__ x,
                                             const float* __restrict__ wq,
                                             const float* __restrict__ wk,
                                             const float* __restrict__ wv,
                                             const float* __restrict__ wproj,
                                             bf16* __restrict__ xb,
                                             bf16* __restrict__ wqb,
                                             bf16* __restrict__ wkb,
                                             bf16* __restrict__ wvb,
                                             bf16* __restrict__ wprojb) {
  const int b = blockIdx.x;
  const float* src; bf16* dst; size_t off;
  if (b < 8192)       { src = x;     dst = xb;     off = (size_t)b * 2048; }
  else if (b < 10240) { src = wq;    dst = wqb;    off = (size_t)(b-8192) * 2048; }
  else if (b < 11264) { src = wk;    dst = wkb;    off = (size_t)(b-10240) * 2048; }
  else if (b < 12288) { src = wv;    dst = wvb;    off = (size_t)(b-11264) * 2048; }
  else                { src = wproj; dst = wprojb; off = (size_t)(b-12288) * 2048; }
  const size_t i = off + (size_t)threadIdx.x * 8;
  *(bf16x8*)(void*)(dst + i) = load8(src + i);
}

// C[m][n] = sum_k A[m][k] * B[n][k], all-bf16 inputs, m97-style DMA staging.
// A row stride lda, B row stride Kd, C row stride ldc.
template<typename TC>
__global__ __launch_bounds__(256) void gemm_bt(const bf16* __restrict__ A,
                                               const bf16* __restrict__ Bw,
                                               TC* __restrict__ Cc,
                                               int M, int N, int Kd,
                                               int lda, int ldc) {
  __shared__ alignas(16) bf16 As[128*64];
  __shared__ alignas(16) bf16 Bs[128*64];
  const int tid = threadIdx.x;
  const int w = tid >> 6, lane = tid & 63;
  const int quad = lane >> 4, l16 = lane & 15;
  const int wm = (w & 1) * 64, wn = (w >> 1) * 64;
  const int m0 = blockIdx.y * 128, n0 = blockIdx.x * 128;
  const int srow = lane >> 3, sseg = lane & 7;

  floatx4 acc[4][4];
  #pragma unroll
  for (int i = 0; i < 4; ++i)
    #pragma unroll
    for (int j = 0; j < 4; ++j) acc[i][j] = (floatx4){0.f, 0.f, 0.f, 0.f};

  for (int k0 = 0; k0 < Kd; k0 += 64) {
    __syncthreads();
    #pragma unroll
    for (int i = 0; i < 4; ++i) {
      const int r  = w*32 + i*8 + srow;
      const int gs = (sseg ^ (r & 7)) * 8;
      gload_lds16(A  + (size_t)(m0 + r)*lda + k0 + gs, As + (w*32 + i*8)*64);
      gload_lds16(Bw + (size_t)(n0 + r)*Kd  + k0 + gs, Bs + (w*32 + i*8)*64);
    }
    __syncthreads();
    #pragma unroll
    for (int kk = 0; kk < 2; ++kk) {
      bf16x8 af[4], bfr[4];
      #pragma unroll
      for (int mt = 0; mt < 4; ++mt) {
        const int m = wm + mt*16 + l16;
        af[mt] = load8(As + m*64 + (((kk*4 + quad) ^ (m & 7)) * 8));
      }
      #pragma unroll
      for (int nt = 0; nt < 4; ++nt) {
        const int n = wn + nt*16 + l16;
        bfr[nt] = load8(Bs + n*64 + (((kk*4 + quad) ^ (n & 7)) * 8));
      }
      #pragma unroll
      for (int mt = 0; mt < 4; ++mt)
        #pragma unroll
        for (int nt = 0; nt < 4; ++nt)
          acc[mt][nt] = mfma16(af[mt], bfr[nt], acc[mt][nt]);
    }
  }

  #pragma unroll
  for (int mt = 0; mt < 4; ++mt)
    #pragma unroll
    for (int r = 0; r < 4; ++r) {
      const size_t row = (size_t)(m0 + wm + mt*16 + quad*4 + r);
      #pragma unroll
      for (int nt = 0; nt < 4; ++nt) {
        const int col = n0 + wn + nt*16 + l16;
        store1(Cc + row*ldc + col, acc[mt][nt][r]);
      }
    }
}

// grid (BT), block 256 (4 waves). One block per token, in-place on QKV.
// Wave w handles 6 of the 24 rope-heads; lane l owns the RoPE pair
// (d=l, d=l+64) so both outputs come from the lane's own two loads.
// cos/sin loaded once per token and reused across all 24 heads.
// Gate dot computed once per (token,hk) by a 32-lane tree (was 128x
// redundant serial loop in the old (BT,32)x128 version, ~220 us total).
__global__ __launch_bounds__(256) void fuse_k(const float* __restrict__ x,
                                              const float* __restrict__ ve,
                                              const float* __restrict__ cosb,
                                              const float* __restrict__ sinb,
                                              const float* __restrict__ wgate,
                                              bf16* __restrict__ QKV) {
  const int tok = blockIdx.x;
  const int t   = tok & (T_ - 1);
  const int tid = threadIdx.x;
  const int w   = tid >> 6, lane = tid & 63;

  __shared__ float gates[8];

  const float c = cosb[t*64 + lane];
  const float s = sinb[t*64 + lane];
  bf16* rowp = QKV + (size_t)tok * QSTR;

  // RoPE + RMS-norm on 16 Q heads + 8 K heads (6 per wave).
  #pragma unroll
  for (int i = 0; i < 6; ++i) {
    const int j = w*6 + i;
    bf16* base = rowp + ((j < 16) ? j * D_ : (KOFF + (j - 16) * D_));
    const float a = __bfloat162float(base[lane]);
    const float b = __bfloat162float(base[lane + 64]);
    const float lo = a*c + b*s;
    const float hi = b*c - a*s;
    float ss = lo*lo + hi*hi;
    #pragma unroll
    for (int off = 1; off < 64; off <<= 1) ss += __shfl_xor(ss, off);
    const float sc = rsqrtf(ss * (1.0f/128.0f) + 1.1920929e-7f);
    base[lane]      = __float2bfloat16(lo * sc);
    base[lane + 64] = __float2bfloat16(hi * sc);
  }

  // Gate: wave w computes hk = 2w (lanes 0-31) and 2w+1 (lanes 32-63).
  {
    const int hk = w*2 + (lane >> 5);
    const int ch = lane & 31;
    float p = x[(size_t)tok * C_ + ch] * wgate[hk*32 + ch];
    #pragma unroll
    for (int off = 1; off < 32; off <<= 1) p += __shfl_xor(p, off);
    if (ch == 0) gates[hk] = 2.0f / (1.0f + __expf(-p));
  }
  __syncthreads();

  // V += gate * ve : 1024 elems, 4 per thread (float4 ve, ushort4 V).
  {
    const int e0 = tid * 4;
    const float g = gates[e0 >> 7];
    const float4 vv = *(const float4*)(ve + (size_t)tok * (HK_*D_) + e0);
    bf16* vp = rowp + VOFF + e0;
    union { ushort4 u; bf16 h[4]; } uu;
    uu.u = *(const ushort4*)(const void*)vp;
    uu.h[0] = __float2bfloat16(__bfloat162float(uu.h[0]) + g * vv.x);
    uu.h[1] = __float2bfloat16(__bfloat162float(uu.h[1]) + g * vv.y);
    uu.h[2] = __float2bfloat16(__bfloat162float(uu.h[2]) + g * vv.z);
    uu.h[3] = __float2bfloat16(__bfloat162float(uu.h[3]) + g * vv.w);
    *(ushort4*)(void*)vp = uu.u;
  }
}

// Flash-style windowed attention on fused QKV [BT,4096]. grid (T/128, H, B),
// block 256 (4 waves). Round-0 structure: 32-key tiles, 3 barriers/tile
// (the pre-PV barrier doubles as a register-pressure fence: removing it
// pushed VGPR 124->136 -> occupancy cliff, round 4), unconditional online-
// softmax rescale (defer-max bookkeeping also costs registers).
// Register-neutral upgrades kept: K staged by DMA (global_load_lds),
// exp2-domain softmax, per-lane l partials reduced once at epilogue.
// NO launch_bounds min-waves arg (round 5: forcing 4 blocks/CU spilled the
// 64-reg accumulator to scratch -> 6x HBM traffic).
// LDS: Ks 8K + Vt 10K + Ps 10K = 28 KB.
__global__ __launch_bounds__(256) void attn_k(bf16* QKV) {
  const int t0 = blockIdx.x * 128;
  const int h  = blockIdx.y, bb = blockIdx.z, hk = h >> 1;
  const int tid = threadIdx.x, w = tid >> 6, lane = tid & 63;
  const int quad = lane >> 4, l16 = lane & 15;
  const int q0 = t0 + w * 32;

  __shared__ alignas(16) bf16 Ks[32*128];   // [key][128], seg-XOR swizzled
  __shared__ alignas(16) bf16 Vt[128*40];   // [d][key] transposed, +8 pad
  __shared__ alignas(16) bf16 Ps[4][32*40]; // per-wave P tile, stride 40

  bf16x8 qf[2][4];
  #pragma unroll
  for (int mt = 0; mt < 2; ++mt)
    #pragma unroll
    for (int kc = 0; kc < 4; ++kc)
      qf[mt][kc] = load8(QKV + (size_t)(bb*T_ + q0 + mt*16 + l16)*QSTR + h*D_ + kc*32 + quad*8);

  floatx4 o[2][8];
  #pragma unroll
  for (int mt = 0; mt < 2; ++mt)
    #pragma unroll
    for (int nt = 0; nt < 8; ++nt) o[mt][nt] = (floatx4){0.f, 0.f, 0.f, 0.f};
  float mr[2][4], lr[2][4];
  #pragma unroll
  for (int mt = 0; mt < 2; ++mt)
    #pragma unroll
    for (int r = 0; r < 4; ++r) { mr[mt][r] = -1.0e30f; lr[mt][r] = 0.f; }

  const int krow_in = lane >> 4;             // 0..3 (K staging row-in-group)
  const int kseg    = lane & 15;             // K staging LDS 16B seg

  const int kb0 = (t0 >= W_) ? (t0 - W_) : 0;
  for (int kb = kb0; kb < t0 + 128; kb += 32) {
    __syncthreads();
    // K: async DMA into seg-swizzled [key][128] (per-lane pre-swizzled source).
    #pragma unroll
    for (int i = 0; i < 2; ++i) {
      const int g = w*2 + i;
      const int krow = g*4 + krow_in;
      const int gseg = (kseg & 8) | ((kseg ^ (krow & 7)) & 7);
      gload_lds16(QKV + (size_t)(bb*T_ + kb + krow)*QSTR + KOFF + hk*D_ + gseg*8,
                  Ks + g*512);
    }
    // V: register transpose into Vt[d][col] (round-0 proven layout)
    #pragma unroll
    for (int jj = 0; jj < 2; ++jj) {
      const int idx = jj*256 + tid;          // 0..511
      const int key = idx >> 4, seg = idx & 15;
      union { bf16x8 v; bf16 hv[8]; } tmp;
      tmp.v = load8(QKV + (size_t)(bb*T_ + kb + key)*QSTR + VOFF + hk*D_ + seg*8);
      const int col = (((key >> 3) ^ (seg & 3)) * 8) + (key & 7);
      #pragma unroll
      for (int e = 0; e < 8; ++e)
        Vt[(seg*8 + e)*40 + col] = tmp.hv[e];
    }
    __syncthreads();

    // QK^T: 8 MFMA over the 32-key tile
    floatx4 s[2][2];
    s[0][0] = (floatx4){0.f,0.f,0.f,0.f}; s[0][1] = (floatx4){0.f,0.f,0.f,0.f};
    s[1][0] = (floatx4){0.f,0.f,0.f,0.f}; s[1][1] = (floatx4){0.f,0.f,0.f,0.f};
    #pragma unroll
    for (int kc = 0; kc < 4; ++kc) {
      const int c8 = kc*4 + quad;
      const int s0 = (c8 & 8) | ((c8 ^ (l16 & 7)) & 7);
      bf16x8 bk0 = load8(Ks + l16*128 + s0*8);
      bf16x8 bk1 = load8(Ks + (16 + l16)*128 + s0*8);
      s[0][0] = mfma16(qf[0][kc], bk0, s[0][0]);
      s[0][1] = mfma16(qf[0][kc], bk1, s[0][1]);
      s[1][0] = mfma16(qf[1][kc], bk0, s[1][0]);
      s[1][1] = mfma16(qf[1][kc], bk1, s[1][1]);
    }

    // Online softmax in log2 domain (unconditional rescale, round-0 style);
    // per-lane l partials (no in-loop reduce).
    const float scale2 = 0.12751744f;  // (1/sqrt(128)) * log2(e)
    #pragma unroll
    for (int mt = 0; mt < 2; ++mt)
      #pragma unroll
      for (int r = 0; r < 4; ++r) {
        const int qg  = q0 + mt*16 + quad*4 + r;
        const int kg0 = kb + l16, kg1 = kb + 16 + l16;
        const float sv0 = (kg0 <= qg && kg0 + W_ >= qg) ? s[mt][0][r]*scale2 : -3.0e38f;
        const float sv1 = (kg1 <= qg && kg1 + W_ >= qg) ? s[mt][1][r]*scale2 : -3.0e38f;
        float mx = fmaxf(sv0, sv1);
        #pragma unroll
        for (int off = 1; off < 16; off <<= 1) mx = fmaxf(mx, __shfl_xor(mx, off));
        const float mnew  = fmaxf(mr[mt][r], mx);
        const float alpha = exp2f(mr[mt][r] - mnew);
        mr[mt][r] = mnew;
        const float p0 = exp2f(sv0 - mnew);
        const float p1 = exp2f(sv1 - mnew);
        lr[mt][r] = lr[mt][r] * alpha + p0 + p1;  // per-lane partial
        const int prow = mt*16 + quad*4 + r;
        Ps[w][prow*40 + l16]      = __float2bfloat16(p0);
        Ps[w][prow*40 + 16 + l16] = __float2bfloat16(p1);
        #pragma unroll
        for (int nt = 0; nt < 8; ++nt) o[mt][nt][r] *= alpha;
      }

    __syncthreads();   // round-0 pre-PV barrier: scheduling/register fence

    bf16x8 pa0 = load8(&Ps[w][l16*40 + quad*8]);
    bf16x8 pa1 = load8(&Ps[w][(16 + l16)*40 + quad*8]);
    #pragma unroll
    for (int nt = 0; nt < 8; ++nt) {
      const int d   = nt*16 + l16;
      const int blk = quad ^ ((d >> 3) & 3);
      bf16x8 bv = load8(Vt + d*40 + blk*8);
      o[0][nt] = mfma16(pa0, bv, o[0][nt]);
      o[1][nt] = mfma16(pa1, bv, o[1][nt]);
    }
  }

  #pragma unroll
  for (int mt = 0; mt < 2; ++mt)
    #pragma unroll
    for (int r = 0; r < 4; ++r) {
      float lt = lr[mt][r];
      #pragma unroll
      for (int off = 1; off < 16; off <<= 1) lt += __shfl_xor(lt, off);
      const float inv = 1.0f / lt;
      const size_t rowoff = (size_t)(bb*T_ + q0 + mt*16 + quad*4 + r) * QSTR + h*D_;
      #pragma unroll
      for (int nt = 0; nt < 8; ++nt)
        QKV[rowoff + nt*16 + l16] = __float2bfloat16(o[mt][nt][r] * inv);
    }
}

extern "C" void kernel_launch(void* const* d_in, const int* in_sizes, int n_in,
                              void* d_out, int out_size, void* d_ws, size_t ws_size,
                              hipStream_t stream) {
  (void)in_sizes; (void)n_in; (void)out_size; (void)ws_size;
  const float* x     = (const float*)d_in[0];
  const float* ve    = (const float*)d_in[1];
  const float* cosb  = (const float*)d_in[2];
  const float* sinb  = (const float*)d_in[3];
  const float* wq    = (const float*)d_in[4];
  const float* wk    = (const float*)d_in[5];
  const float* wv    = (const float*)d_in[6];
  const float* wproj = (const float*)d_in[7];
  const float* wgate = (const float*)d_in[8];

  // ws layout (75.5 MB): QKV [BT,4096] | wprojb [2048,2048]
  bf16* QKV    = (bf16*)d_ws;
  bf16* wprojb = QKV + (size_t)BT_ * QSTR;

  // Transient bf16 copies live INSIDE d_out (f32): dead before final GEMM.
  // wq|wk|wv rows are contiguous -> fused [4096,2048] QKV weight.
  bf16* xb    = (bf16*)d_out;
  bf16* wqkvb = xb  + (size_t)BT_ * C_;
  bf16* wqb   = wqkvb;
  bf16* wkb   = wqb + (size_t)C_ * C_;
  bf16* wvb   = wkb + (size_t)(HK_*D_) * C_;

  cvt_k<<<14336, 256, 0, stream>>>(x, wq, wk, wv, wproj, xb, wqb, wkb, wvb, wprojb);
  gemm_bt<bf16><<<dim3(QSTR/128, BT_/128), 256, 0, stream>>>(xb, wqkvb, QKV,
                                                             BT_, QSTR, C_, C_, QSTR);
  fuse_k<<<BT_, 256, 0, stream>>>(x, ve, cosb, sinb, wgate, QKV);
  attn_k<<<dim3(T_/128, H_, B_), 256, 0, stream>>>(QKV);
  gemm_bt<float><<<dim3(C_/128, BT_/128), 256, 0, stream>>>(QKV, wprojb, (float*)d_out,
                                                            BT_, C_, C_, QSTR, C_);
}

// Round 8
// 535.792 us; speedup vs baseline: 1.4468x; 1.0518x over previous
//
#include <hip/hip_runtime.h>
#include <hip/hip_bf16.h>
#include <cstdint>
#include <cstddef>

using bf16 = __hip_bfloat16;
typedef __bf16 bf16x8 __attribute__((ext_vector_type(8)));
typedef float floatx4 __attribute__((ext_vector_type(4)));

#define B_  2
#define T_  4096
#define C_  2048
#define H_  16
#define HK_ 8
#define D_  128
#define W_  512
#define BT_ (B_*T_)
#define QSTR 4096          // row stride of fused QKV buffer
#define KOFF 2048          // K column offset in QKV
#define VOFF 3072          // V column offset in QKV

__device__ __forceinline__ void gload_lds16(const void* g, void* l) {
  __builtin_amdgcn_global_load_lds((const __attribute__((address_space(1))) void*)g,
                                   (__attribute__((address_space(3))) void*)l, 16, 0, 0);
}
__device__ __forceinline__ floatx4 mfma16(bf16x8 a, bf16x8 b, floatx4 c) {
  return __builtin_amdgcn_mfma_f32_16x16x32_bf16(a, b, c, 0, 0, 0);
}
__device__ __forceinline__ __bf16 f2b(float f) {
  union { bf16 h; __bf16 b; } u; u.h = __float2bfloat16(f); return u.b;
}
__device__ __forceinline__ bf16x8 load8(const bf16* p) {
  return *(const bf16x8*)(const void*)p;
}
__device__ __forceinline__ bf16x8 load8(const float* p) {
  float4 a = *(const float4*)(const void*)p;
  float4 b = *(const float4*)(const void*)(p + 4);
  bf16x8 r;
  r[0]=f2b(a.x); r[1]=f2b(a.y); r[2]=f2b(a.z); r[3]=f2b(a.w);
  r[4]=f2b(b.x); r[5]=f2b(b.y); r[6]=f2b(b.z); r[7]=f2b(b.w);
  return r;
}
__device__ __forceinline__ void store1(float* p, float v) { *p = v; }
__device__ __forceinline__ void store1(bf16*  p, float v) { *p = __float2bfloat16(v); }

// One-shot f32 -> bf16 conversion of x and the four weight matrices.
// wq/wk/wv land contiguously -> one [4096, 2048] fused QKV weight.
__global__ __launch_bounds__(256) void cvt_k(const float* __restrict__ x,
                                             const float* __restrict__ wq,
                                             const float* __restrict__ wk,
                                             const float* __restrict__ wv,
                                             const float* __restrict__ wproj,
                                             bf16* __restrict__ xb,
                                             bf16* __restrict__ wqb,
                                             bf16* __restrict__ wkb,
                                             bf16* __restrict__ wvb,
                                             bf16* __restrict__ wprojb) {
  const int b = blockIdx.x;
  const float* src; bf16* dst; size_t off;
  if (b < 8192)       { src = x;     dst = xb;     off = (size_t)b * 2048; }
  else if (b < 10240) { src = wq;    dst = wqb;    off = (size_t)(b-8192) * 2048; }
  else if (b < 11264) { src = wk;    dst = wkb;    off = (size_t)(b-10240) * 2048; }
  else if (b < 12288) { src = wv;    dst = wvb;    off = (size_t)(b-11264) * 2048; }
  else                { src = wproj; dst = wprojb; off = (size_t)(b-12288) * 2048; }
  const size_t i = off + (size_t)threadIdx.x * 8;
  *(bf16x8*)(void*)(dst + i) = load8(src + i);
}

// C[m][n] = sum_k A[m][k] * B[n][k], all-bf16 inputs, m97-style DMA staging.
// A row stride lda, B row stride Kd, C row stride ldc.
template<typename TC>
__global__ __launch_bounds__(256) void gemm_bt(const bf16* __restrict__ A,
                                               const bf16* __restrict__ Bw,
                                               TC* __restrict__ Cc,
                                               int M, int N, int Kd,
                                               int lda, int ldc) {
  __shared__ alignas(16) bf16 As[128*64];
  __shared__ alignas(16) bf16 Bs[128*64];
  const int tid = threadIdx.x;
  const int w = tid >> 6, lane = tid & 63;
  const int quad = lane >> 4, l16 = lane & 15;
  const int wm = (w & 1) * 64, wn = (w >> 1) * 64;
  const int m0 = blockIdx.y * 128, n0 = blockIdx.x * 128;
  const int srow = lane >> 3, sseg = lane & 7;

  floatx4 acc[4][4];
  #pragma unroll
  for (int i = 0; i < 4; ++i)
    #pragma unroll
    for (int j = 0; j < 4; ++j) acc[i][j] = (floatx4){0.f, 0.f, 0.f, 0.f};

  for (int k0 = 0; k0 < Kd; k0 += 64) {
    __syncthreads();
    #pragma unroll
    for (int i = 0; i < 4; ++i) {
      const int r  = w*32 + i*8 + srow;
      const int gs = (sseg ^ (r & 7)) * 8;
      gload_lds16(A  + (size_t)(m0 + r)*lda + k0 + gs, As + (w*32 + i*8)*64);
      gload_lds16(Bw + (size_t)(n0 + r)*Kd  + k0 + gs, Bs + (w*32 + i*8)*64);
    }
    __syncthreads();
    #pragma unroll
    for (int kk = 0; kk < 2; ++kk) {
      bf16x8 af[4], bfr[4];
      #pragma unroll
      for (int mt = 0; mt < 4; ++mt) {
        const int m = wm + mt*16 + l16;
        af[mt] = load8(As + m*64 + (((kk*4 + quad) ^ (m & 7)) * 8));
      }
      #pragma unroll
      for (int nt = 0; nt < 4; ++nt) {
        const int n = wn + nt*16 + l16;
        bfr[nt] = load8(Bs + n*64 + (((kk*4 + quad) ^ (n & 7)) * 8));
      }
      #pragma unroll
      for (int mt = 0; mt < 4; ++mt)
        #pragma unroll
        for (int nt = 0; nt < 4; ++nt)
          acc[mt][nt] = mfma16(af[mt], bfr[nt], acc[mt][nt]);
    }
  }

  #pragma unroll
  for (int mt = 0; mt < 4; ++mt)
    #pragma unroll
    for (int r = 0; r < 4; ++r) {
      const size_t row = (size_t)(m0 + wm + mt*16 + quad*4 + r);
      #pragma unroll
      for (int nt = 0; nt < 4; ++nt) {
        const int col = n0 + wn + nt*16 + l16;
        store1(Cc + row*ldc + col, acc[mt][nt][r]);
      }
    }
}

// grid (BT), block 256 (4 waves). One block per token, in-place on QKV.
__global__ __launch_bounds__(256) void fuse_k(const float* __restrict__ x,
                                              const float* __restrict__ ve,
                                              const float* __restrict__ cosb,
                                              const float* __restrict__ sinb,
                                              const float* __restrict__ wgate,
                                              bf16* __restrict__ QKV) {
  const int tok = blockIdx.x;
  const int t   = tok & (T_ - 1);
  const int tid = threadIdx.x;
  const int w   = tid >> 6, lane = tid & 63;

  __shared__ float gates[8];

  const float c = cosb[t*64 + lane];
  const float s = sinb[t*64 + lane];
  bf16* rowp = QKV + (size_t)tok * QSTR;

  // RoPE + RMS-norm on 16 Q heads + 8 K heads (6 per wave).
  #pragma unroll
  for (int i = 0; i < 6; ++i) {
    const int j = w*6 + i;
    bf16* base = rowp + ((j < 16) ? j * D_ : (KOFF + (j - 16) * D_));
    const float a = __bfloat162float(base[lane]);
    const float b = __bfloat162float(base[lane + 64]);
    const float lo = a*c + b*s;
    const float hi = b*c - a*s;
    float ss = lo*lo + hi*hi;
    #pragma unroll
    for (int off = 1; off < 64; off <<= 1) ss += __shfl_xor(ss, off);
    const float sc = rsqrtf(ss * (1.0f/128.0f) + 1.1920929e-7f);
    base[lane]      = __float2bfloat16(lo * sc);
    base[lane + 64] = __float2bfloat16(hi * sc);
  }

  // Gate: wave w computes hk = 2w (lanes 0-31) and 2w+1 (lanes 32-63).
  {
    const int hk = w*2 + (lane >> 5);
    const int ch = lane & 31;
    float p = x[(size_t)tok * C_ + ch] * wgate[hk*32 + ch];
    #pragma unroll
    for (int off = 1; off < 32; off <<= 1) p += __shfl_xor(p, off);
    if (ch == 0) gates[hk] = 2.0f / (1.0f + __expf(-p));
  }
  __syncthreads();

  // V += gate * ve : 1024 elems, 4 per thread (float4 ve, ushort4 V).
  {
    const int e0 = tid * 4;
    const float g = gates[e0 >> 7];
    const float4 vv = *(const float4*)(ve + (size_t)tok * (HK_*D_) + e0);
    bf16* vp = rowp + VOFF + e0;
    union { ushort4 u; bf16 h[4]; } uu;
    uu.u = *(const ushort4*)(const void*)vp;
    uu.h[0] = __float2bfloat16(__bfloat162float(uu.h[0]) + g * vv.x);
    uu.h[1] = __float2bfloat16(__bfloat162float(uu.h[1]) + g * vv.y);
    uu.h[2] = __float2bfloat16(__bfloat162float(uu.h[2]) + g * vv.z);
    uu.h[3] = __float2bfloat16(__bfloat162float(uu.h[3]) + g * vv.w);
    *(ushort4*)(void*)vp = uu.u;
  }
}

// V transpose: VT[bb][hk][d][t] = V[bb][t][hk][d] (post gate update).
// grid (T/64, D/64, B*HK), block 256. LDS 64x72 tile (16B-aligned rows).
__global__ __launch_bounds__(256) void vt_k(const bf16* __restrict__ QKV,
                                            bf16* __restrict__ VT) {
  const int t0 = blockIdx.x * 64;
  const int d0 = blockIdx.y * 64;
  const int bh = blockIdx.z;              // bb*8 + hk
  const int bb = bh >> 3, hk = bh & 7;
  const int tid = threadIdx.x;
  __shared__ alignas(16) bf16 Ts[64][72];

  #pragma unroll
  for (int it = 0; it < 2; ++it) {
    const int row = (tid >> 3) + it*32;   // t-local 0..63
    const int c8  = tid & 7;              // d-local 16B seg
    *(bf16x8*)(void*)&Ts[row][c8*8] =
      load8(QKV + (size_t)(bb*T_ + t0 + row)*QSTR + VOFF + hk*D_ + d0 + c8*8);
  }
  __syncthreads();
  #pragma unroll
  for (int it = 0; it < 2; ++it) {
    const int dr   = tid >> 2;            // d-local 0..63
    const int tblk = (tid & 3) + it*4;    // t-local 16B seg 0..7
    union { bf16x8 v; bf16 h[8]; } u;
    #pragma unroll
    for (int e = 0; e < 8; ++e) u.h[e] = Ts[tblk*8 + e][dr];
    *(bf16x8*)(void*)(VT + ((size_t)bh*D_ + d0 + dr)*T_ + t0 + tblk*8) = u.v;
  }
}

// Flash-style windowed attention on fused QKV [BT,4096]. grid (T/128, H, B),
// block 256 (4 waves). 32-key tiles, K and V^T staged by DMA.
// FIXED-MAX softmax: Q,K are RMS-normed so |q·k|*scale*log2e <= 16.45
// (Cauchy-Schwarz; |q|^2 = 128*(1 +- bf16 rounding)). Use constant max
// FM = 16.55: p = exp2(s' - FM). Diagonal (always in-window) gives
// p ~ 0.9 -> well-scaled; softmax shift-invariance makes output exact.
// Removes ALL online-max state (mr), shuffle-max trees, alpha rescales.
// LDS: Ks 8K + Vt 8K (linear [128][32], DMA'd from VT) + Ps 10K = 26 KB.
__global__ __launch_bounds__(256) void attn_k(bf16* QKV,
                                              const bf16* __restrict__ VT) {
  const int t0 = blockIdx.x * 128;
  const int h  = blockIdx.y, bb = blockIdx.z, hk = h >> 1;
  const int tid = threadIdx.x, w = tid >> 6, lane = tid & 63;
  const int quad = lane >> 4, l16 = lane & 15;
  const int q0 = t0 + w * 32;

  __shared__ alignas(16) bf16 Ks[32*128];   // [key][128], seg-XOR swizzled
  __shared__ alignas(16) bf16 Vt[128*32];   // [d][key] linear, from VT
  __shared__ alignas(16) bf16 Ps[4][32*40]; // per-wave P tile, stride 40

  bf16x8 qf[2][4];
  #pragma unroll
  for (int mt = 0; mt < 2; ++mt)
    #pragma unroll
    for (int kc = 0; kc < 4; ++kc)
      qf[mt][kc] = load8(QKV + (size_t)(bb*T_ + q0 + mt*16 + l16)*QSTR + h*D_ + kc*32 + quad*8);

  floatx4 o[2][8];
  #pragma unroll
  for (int mt = 0; mt < 2; ++mt)
    #pragma unroll
    for (int nt = 0; nt < 8; ++nt) o[mt][nt] = (floatx4){0.f, 0.f, 0.f, 0.f};
  float lr[2][4];
  #pragma unroll
  for (int mt = 0; mt < 2; ++mt)
    #pragma unroll
    for (int r = 0; r < 4; ++r) lr[mt][r] = 0.f;

  const int krow_in = lane >> 4;             // 0..3 (K staging row-in-group)
  const int kseg    = lane & 15;             // K staging LDS 16B seg
  const bf16* VTh = VT + (size_t)(bb*HK_ + hk) * D_ * T_;

  const int kb0 = (t0 >= W_) ? (t0 - W_) : 0;
  for (int kb = kb0; kb < t0 + 128; kb += 32) {
    __syncthreads();
    // K: async DMA into seg-swizzled [key][128] (per-lane pre-swizzled source).
    #pragma unroll
    for (int i = 0; i < 2; ++i) {
      const int g = w*2 + i;
      const int krow = g*4 + krow_in;
      const int gseg = (kseg & 8) | ((kseg ^ (krow & 7)) & 7);
      gload_lds16(QKV + (size_t)(bb*T_ + kb + krow)*QSTR + KOFF + hk*D_ + gseg*8,
                  Ks + g*512);
    }
    // V: async DMA from VT rows into linear Vt[d][32] (chunk c -> d=c>>2).
    #pragma unroll
    for (int i = 0; i < 2; ++i) {
      const int c  = (w*2 + i)*64 + lane;    // 16B chunk 0..511
      const int vd = c >> 2, kblk = c & 3;
      gload_lds16(VTh + (size_t)vd*T_ + kb + kblk*8,
                  Vt + (w*2 + i)*512);
    }
    __syncthreads();

    // QK^T: 16 MFMA over the 32-key tile
    floatx4 s[2][2];
    s[0][0] = (floatx4){0.f,0.f,0.f,0.f}; s[0][1] = (floatx4){0.f,0.f,0.f,0.f};
    s[1][0] = (floatx4){0.f,0.f,0.f,0.f}; s[1][1] = (floatx4){0.f,0.f,0.f,0.f};
    #pragma unroll
    for (int kc = 0; kc < 4; ++kc) {
      const int c8 = kc*4 + quad;
      const int s0 = (c8 & 8) | ((c8 ^ (l16 & 7)) & 7);
      bf16x8 bk0 = load8(Ks + l16*128 + s0*8);
      bf16x8 bk1 = load8(Ks + (16 + l16)*128 + s0*8);
      s[0][0] = mfma16(qf[0][kc], bk0, s[0][0]);
      s[0][1] = mfma16(qf[0][kc], bk1, s[0][1]);
      s[1][0] = mfma16(qf[1][kc], bk0, s[1][0]);
      s[1][1] = mfma16(qf[1][kc], bk1, s[1][1]);
    }

    // Fixed-max softmax: p = exp2(s*scale2 - FM), no max tracking at all.
    const float scale2 = 0.12751744f;  // (1/sqrt(128)) * log2(e)
    const float FM     = 16.55f;       // >= max possible |s|*scale2 (16.45)
    #pragma unroll
    for (int mt = 0; mt < 2; ++mt)
      #pragma unroll
      for (int r = 0; r < 4; ++r) {
        const int qg  = q0 + mt*16 + quad*4 + r;
        const int kg0 = kb + l16, kg1 = kb + 16 + l16;
        const float sv0 = (kg0 <= qg && kg0 + W_ >= qg) ? s[mt][0][r]*scale2 - FM : -3.0e38f;
        const float sv1 = (kg1 <= qg && kg1 + W_ >= qg) ? s[mt][1][r]*scale2 - FM : -3.0e38f;
        const float p0 = exp2f(sv0);
        const float p1 = exp2f(sv1);
        lr[mt][r] += p0 + p1;              // per-lane partial; reduced at epilogue
        const int prow = mt*16 + quad*4 + r;
        Ps[w][prow*40 + l16]      = __float2bfloat16(p0);
        Ps[w][prow*40 + 16 + l16] = __float2bfloat16(p1);
      }

    __syncthreads();   // pre-PV barrier: scheduling/register fence (r4 lesson)

    bf16x8 pa0 = load8(&Ps[w][l16*40 + quad*8]);
    bf16x8 pa1 = load8(&Ps[w][(16 + l16)*40 + quad*8]);
    #pragma unroll
    for (int nt = 0; nt < 8; ++nt) {
      const int d = nt*16 + l16;
      bf16x8 bv = load8(Vt + d*32 + quad*8);
      o[0][nt] = mfma16(pa0, bv, o[0][nt]);
      o[1][nt] = mfma16(pa1, bv, o[1][nt]);
    }
  }

  #pragma unroll
  for (int mt = 0; mt < 2; ++mt)
    #pragma unroll
    for (int r = 0; r < 4; ++r) {
      float lt = lr[mt][r];
      #pragma unroll
      for (int off = 1; off < 16; off <<= 1) lt += __shfl_xor(lt, off);
      const float inv = 1.0f / lt;
      const size_t rowoff = (size_t)(bb*T_ + q0 + mt*16 + quad*4 + r) * QSTR + h*D_;
      #pragma unroll
      for (int nt = 0; nt < 8; ++nt)
        QKV[rowoff + nt*16 + l16] = __float2bfloat16(o[mt][nt][r] * inv);
    }
}

extern "C" void kernel_launch(void* const* d_in, const int* in_sizes, int n_in,
                              void* d_out, int out_size, void* d_ws, size_t ws_size,
                              hipStream_t stream) {
  (void)in_sizes; (void)n_in; (void)out_size; (void)ws_size;
  const float* x     = (const float*)d_in[0];
  const float* ve    = (const float*)d_in[1];
  const float* cosb  = (const float*)d_in[2];
  const float* sinb  = (const float*)d_in[3];
  const float* wq    = (const float*)d_in[4];
  const float* wk    = (const float*)d_in[5];
  const float* wv    = (const float*)d_in[6];
  const float* wproj = (const float*)d_in[7];
  const float* wgate = (const float*)d_in[8];

  // ws layout: QKV [BT,4096] (64MB) | wprojb [2048,2048] (8.4MB)
  bf16* QKV    = (bf16*)d_ws;
  bf16* wprojb = QKV + (size_t)BT_ * QSTR;

  // d_out (67.1MB f32) doubles as scratch: xb (33.55) | wqkvb (16.78) |
  // VT (16.78) -- all dead before the final GEMM overwrites d_out.
  bf16* xb    = (bf16*)d_out;
  bf16* wqkvb = xb  + (size_t)BT_ * C_;
  bf16* wqb   = wqkvb;
  bf16* wkb   = wqb + (size_t)C_ * C_;
  bf16* wvb   = wkb + (size_t)(HK_*D_) * C_;
  bf16* VT    = wqkvb + (size_t)QSTR * C_;      // [B*HK][D][T] = 16.78MB

  cvt_k<<<14336, 256, 0, stream>>>(x, wq, wk, wv, wproj, xb, wqb, wkb, wvb, wprojb);
  gemm_bt<bf16><<<dim3(QSTR/128, BT_/128), 256, 0, stream>>>(xb, wqkvb, QKV,
                                                             BT_, QSTR, C_, C_, QSTR);
  fuse_k<<<BT_, 256, 0, stream>>>(x, ve, cosb, sinb, wgate, QKV);
  vt_k<<<dim3(T_/64, D_/64, B_*HK_), 256, 0, stream>>>(QKV, VT);
  attn_k<<<dim3(T_/128, H_, B_), 256, 0, stream>>>(QKV, VT);
  gemm_bt<float><<<dim3(C_/128, BT_/128), 256, 0, stream>>>(QKV, wprojb, (float*)d_out,
                                                            BT_, C_, C_, QSTR, C_);
}

// Round 9
// 520.485 us; speedup vs baseline: 1.4893x; 1.0294x over previous
//
#include <hip/hip_runtime.h>
#include <hip/hip_bf16.h>
#include <cstdint>
#include <cstddef>

using bf16 = __hip_bfloat16;
typedef __bf16 bf16x8 __attribute__((ext_vector_type(8)));
typedef float floatx4 __attribute__((ext_vector_type(4)));

#define B_  2
#define T_  4096
#define C_  2048
#define H_  16
#define HK_ 8
#define D_  128
#define W_  512
#define BT_ (B_*T_)
#define QSTR 4096          // row stride of fused QKV buffer
#define KOFF 2048          // K column offset in QKV
#define VOFF 3072          // V column offset in QKV

__device__ __forceinline__ void gload_lds16(const void* g, void* l) {
  __builtin_amdgcn_global_load_lds((const __attribute__((address_space(1))) void*)g,
                                   (__attribute__((address_space(3))) void*)l, 16, 0, 0);
}
__device__ __forceinline__ floatx4 mfma16(bf16x8 a, bf16x8 b, floatx4 c) {
  return __builtin_amdgcn_mfma_f32_16x16x32_bf16(a, b, c, 0, 0, 0);
}
__device__ __forceinline__ __bf16 f2b(float f) {
  union { bf16 h; __bf16 b; } u; u.h = __float2bfloat16(f); return u.b;
}
__device__ __forceinline__ bf16x8 load8(const bf16* p) {
  return *(const bf16x8*)(const void*)p;
}
__device__ __forceinline__ bf16x8 load8(const float* p) {
  float4 a = *(const float4*)(const void*)p;
  float4 b = *(const float4*)(const void*)(p + 4);
  bf16x8 r;
  r[0]=f2b(a.x); r[1]=f2b(a.y); r[2]=f2b(a.z); r[3]=f2b(a.w);
  r[4]=f2b(b.x); r[5]=f2b(b.y); r[6]=f2b(b.z); r[7]=f2b(b.w);
  return r;
}
__device__ __forceinline__ void store1(float* p, float v) { *p = v; }
__device__ __forceinline__ void store1(bf16*  p, float v) { *p = __float2bfloat16(v); }

// One-shot f32 -> bf16 conversion of x and the four weight matrices.
// wq/wk/wv land contiguously -> one [4096, 2048] fused QKV weight.
__global__ __launch_bounds__(256) void cvt_k(const float* __restrict__ x,
                                             const float* __restrict__ wq,
                                             const float* __restrict__ wk,
                                             const float* __restrict__ wv,
                                             const float* __restrict__ wproj,
                                             bf16* __restrict__ xb,
                                             bf16* __restrict__ wqb,
                                             bf16* __restrict__ wkb,
                                             bf16* __restrict__ wvb,
                                             bf16* __restrict__ wprojb) {
  const int b = blockIdx.x;
  const float* src; bf16* dst; size_t off;
  if (b < 8192)       { src = x;     dst = xb;     off = (size_t)b * 2048; }
  else if (b < 10240) { src = wq;    dst = wqb;    off = (size_t)(b-8192) * 2048; }
  else if (b < 11264) { src = wk;    dst = wkb;    off = (size_t)(b-10240) * 2048; }
  else if (b < 12288) { src = wv;    dst = wvb;    off = (size_t)(b-11264) * 2048; }
  else                { src = wproj; dst = wprojb; off = (size_t)(b-12288) * 2048; }
  const size_t i = off + (size_t)threadIdx.x * 8;
  *(bf16x8*)(void*)(dst + i) = load8(src + i);
}

// 256x256-tile deep-pipelined GEMM: C[m][n] = sum_k A[m][k]*B[n][k].
// 8 waves (2M x 4N), BK=64, LDS 128KB double-buffer -> 1 block/CU.
// Schedule (T3+T4+T5, derived + race-checked by construction):
//   prologue: STAGE(0,buf0); STAGE(1,buf1)            [16 loads in flight]
//   iter j:   vmcnt(8)  <- drains exactly tile j (oldest 8), j+1/j+2 fly
//             barrier
//             4 phases x { ds_read frags; barrier; setprio(1); 16 MFMA;
//                          setprio(0); barrier }      (B-frags read once)
//             STAGE(j+2, buf j&1)  <- buffer j&1 free: every wave passed
//                lgkmcnt(0) (before its MFMAs) + the final phase barrier,
//                so no ds_read of tile j can still be pending when the
//                DMA writes land. DMA target != buffer read by iter j+1.
//   vmcnt(0) only on the last iteration.
// Fragment math/swizzle/epilogue identical to the verified 128^2 kernel
// (seg^(row&7) pre-swizzled global source; measured 0 bank conflicts).
template<typename TC>
__global__ __launch_bounds__(512, 2) void gemm8(const bf16* __restrict__ A,
                                                const bf16* __restrict__ Bw,
                                                TC* __restrict__ Cc,
                                                int M, int N, int Kd,
                                                int lda, int ldc) {
  __shared__ alignas(16) bf16 As[2][256*64];
  __shared__ alignas(16) bf16 Bs[2][256*64];
  const int tid = threadIdx.x;
  const int lane = tid & 63, wid = tid >> 6;
  const int quad = lane >> 4, l16 = lane & 15;
  const int wm = (wid >> 2) * 128;   // wave row block (2 waves in M)
  const int wn = (wid & 3) * 64;     // wave col block (4 waves in N)
  const int m0 = blockIdx.y * 256, n0 = blockIdx.x * 256;
  const int srow = tid >> 3;         // 0..63: staging row within 64-row batch
  const int sseg = tid & 7;          // staging 16B seg within 128B row

  floatx4 acc[8][4];
  #pragma unroll
  for (int i = 0; i < 8; ++i)
    #pragma unroll
    for (int j = 0; j < 4; ++j) acc[i][j] = (floatx4){0.f, 0.f, 0.f, 0.f};

  const int NT = Kd >> 6;

  auto STAGE = [&](int kt, int b) {
    const int k0 = kt << 6;
    bf16* Ad = &As[b][0];
    bf16* Bd = &Bs[b][0];
    #pragma unroll
    for (int i = 0; i < 4; ++i) {
      const int r  = i*64 + srow;                    // tile row 0..255
      const int gs = (sseg ^ (r & 7)) * 8;           // pre-swizzled global seg
      gload_lds16(A  + (size_t)(m0 + r)*lda + k0 + gs, Ad + r*64 + sseg*8);
      gload_lds16(Bw + (size_t)(n0 + r)*Kd  + k0 + gs, Bd + r*64 + sseg*8);
    }
  };

  STAGE(0, 0);
  STAGE(1, 1);

  for (int j = 0; j < NT; ++j) {
    if (j < NT - 1) asm volatile("s_waitcnt vmcnt(8)" ::: "memory");
    else            asm volatile("s_waitcnt vmcnt(0)" ::: "memory");
    __builtin_amdgcn_s_barrier();

    const bf16* Ab = &As[j & 1][0];
    const bf16* Bb = &Bs[j & 1][0];
    bf16x8 bfr[4][2];

    #pragma unroll
    for (int p = 0; p < 4; ++p) {
      if (p == 0) {
        #pragma unroll
        for (int nt = 0; nt < 4; ++nt)
          #pragma unroll
          for (int kk = 0; kk < 2; ++kk) {
            const int n = wn + nt*16 + l16;
            bfr[nt][kk] = load8(Bb + n*64 + (((kk*4 + quad) ^ (n & 7)) * 8));
          }
      }
      bf16x8 af[2][2];
      #pragma unroll
      for (int i = 0; i < 2; ++i)
        #pragma unroll
        for (int kk = 0; kk < 2; ++kk) {
          const int m = wm + (p*2 + i)*16 + l16;
          af[i][kk] = load8(Ab + m*64 + (((kk*4 + quad) ^ (m & 7)) * 8));
        }
      __builtin_amdgcn_s_barrier();
      __builtin_amdgcn_s_setprio(1);
      #pragma unroll
      for (int i = 0; i < 2; ++i)
        #pragma unroll
        for (int nt = 0; nt < 4; ++nt)
          #pragma unroll
          for (int kk = 0; kk < 2; ++kk)
            acc[p*2 + i][nt] = mfma16(af[i][kk], bfr[nt][kk], acc[p*2 + i][nt]);
      __builtin_amdgcn_s_setprio(0);
      __builtin_amdgcn_s_barrier();
    }

    if (j + 2 < NT) STAGE(j + 2, j & 1);
  }

  #pragma unroll
  for (int mt = 0; mt < 8; ++mt)
    #pragma unroll
    for (int r = 0; r < 4; ++r) {
      const size_t row = (size_t)(m0 + wm + mt*16 + quad*4 + r);
      #pragma unroll
      for (int nt = 0; nt < 4; ++nt) {
        const int col = n0 + wn + nt*16 + l16;
        store1(Cc + row*ldc + col, acc[mt][nt][r]);
      }
    }
}

// grid (BT), block 256 (4 waves). One block per token, in-place on QKV.
__global__ __launch_bounds__(256) void fuse_k(const float* __restrict__ x,
                                              const float* __restrict__ ve,
                                              const float* __restrict__ cosb,
                                              const float* __restrict__ sinb,
                                              const float* __restrict__ wgate,
                                              bf16* __restrict__ QKV) {
  const int tok = blockIdx.x;
  const int t   = tok & (T_ - 1);
  const int tid = threadIdx.x;
  const int w   = tid >> 6, lane = tid & 63;

  __shared__ float gates[8];

  const float c = cosb[t*64 + lane];
  const float s = sinb[t*64 + lane];
  bf16* rowp = QKV + (size_t)tok * QSTR;

  // RoPE + RMS-norm on 16 Q heads + 8 K heads (6 per wave).
  #pragma unroll
  for (int i = 0; i < 6; ++i) {
    const int j = w*6 + i;
    bf16* base = rowp + ((j < 16) ? j * D_ : (KOFF + (j - 16) * D_));
    const float a = __bfloat162float(base[lane]);
    const float b = __bfloat162float(base[lane + 64]);
    const float lo = a*c + b*s;
    const float hi = b*c - a*s;
    float ss = lo*lo + hi*hi;
    #pragma unroll
    for (int off = 1; off < 64; off <<= 1) ss += __shfl_xor(ss, off);
    const float sc = rsqrtf(ss * (1.0f/128.0f) + 1.1920929e-7f);
    base[lane]      = __float2bfloat16(lo * sc);
    base[lane + 64] = __float2bfloat16(hi * sc);
  }

  // Gate: wave w computes hk = 2w (lanes 0-31) and 2w+1 (lanes 32-63).
  {
    const int hk = w*2 + (lane >> 5);
    const int ch = lane & 31;
    float p = x[(size_t)tok * C_ + ch] * wgate[hk*32 + ch];
    #pragma unroll
    for (int off = 1; off < 32; off <<= 1) p += __shfl_xor(p, off);
    if (ch == 0) gates[hk] = 2.0f / (1.0f + __expf(-p));
  }
  __syncthreads();

  // V += gate * ve : 1024 elems, 4 per thread (float4 ve, ushort4 V).
  {
    const int e0 = tid * 4;
    const float g = gates[e0 >> 7];
    const float4 vv = *(const float4*)(ve + (size_t)tok * (HK_*D_) + e0);
    bf16* vp = rowp + VOFF + e0;
    union { ushort4 u; bf16 h[4]; } uu;
    uu.u = *(const ushort4*)(const void*)vp;
    uu.h[0] = __float2bfloat16(__bfloat162float(uu.h[0]) + g * vv.x);
    uu.h[1] = __float2bfloat16(__bfloat162float(uu.h[1]) + g * vv.y);
    uu.h[2] = __float2bfloat16(__bfloat162float(uu.h[2]) + g * vv.z);
    uu.h[3] = __float2bfloat16(__bfloat162float(uu.h[3]) + g * vv.w);
    *(ushort4*)(void*)vp = uu.u;
  }
}

// V transpose: VT[bb][hk][d][t] = V[bb][t][hk][d] (post gate update).
// grid (T/64, D/64, B*HK), block 256. LDS 64x72 tile (16B-aligned rows).
__global__ __launch_bounds__(256) void vt_k(const bf16* __restrict__ QKV,
                                            bf16* __restrict__ VT) {
  const int t0 = blockIdx.x * 64;
  const int d0 = blockIdx.y * 64;
  const int bh = blockIdx.z;              // bb*8 + hk
  const int bb = bh >> 3, hk = bh & 7;
  const int tid = threadIdx.x;
  __shared__ alignas(16) bf16 Ts[64][72];

  #pragma unroll
  for (int it = 0; it < 2; ++it) {
    const int row = (tid >> 3) + it*32;   // t-local 0..63
    const int c8  = tid & 7;              // d-local 16B seg
    *(bf16x8*)(void*)&Ts[row][c8*8] =
      load8(QKV + (size_t)(bb*T_ + t0 + row)*QSTR + VOFF + hk*D_ + d0 + c8*8);
  }
  __syncthreads();
  #pragma unroll
  for (int it = 0; it < 2; ++it) {
    const int dr   = tid >> 2;            // d-local 0..63
    const int tblk = (tid & 3) + it*4;    // t-local 16B seg 0..7
    union { bf16x8 v; bf16 h[8]; } u;
    #pragma unroll
    for (int e = 0; e < 8; ++e) u.h[e] = Ts[tblk*8 + e][dr];
    *(bf16x8*)(void*)(VT + ((size_t)bh*D_ + d0 + dr)*T_ + t0 + tblk*8) = u.v;
  }
}

// Flash-style windowed attention on fused QKV [BT,4096]. grid (T/128, H, B),
// block 256 (4 waves). 32-key tiles, K and V^T staged by DMA.
// FIXED-MAX softmax: Q,K are RMS-normed so |q·k|*scale*log2e <= 16.45
// (Cauchy-Schwarz). Constant max FM = 16.55: p = exp2(s' - FM); softmax
// shift-invariance makes the output exact; diagonal keeps p well-scaled.
// LDS: Ks 8K + Vt 8K (linear, DMA'd from VT) + Ps 10K = 26 KB.
__global__ __launch_bounds__(256) void attn_k(bf16* QKV,
                                              const bf16* __restrict__ VT) {
  const int t0 = blockIdx.x * 128;
  const int h  = blockIdx.y, bb = blockIdx.z, hk = h >> 1;
  const int tid = threadIdx.x, w = tid >> 6, lane = tid & 63;
  const int quad = lane >> 4, l16 = lane & 15;
  const int q0 = t0 + w * 32;

  __shared__ alignas(16) bf16 Ks[32*128];   // [key][128], seg-XOR swizzled
  __shared__ alignas(16) bf16 Vt[128*32];   // [d][key] linear, from VT
  __shared__ alignas(16) bf16 Ps[4][32*40]; // per-wave P tile, stride 40

  bf16x8 qf[2][4];
  #pragma unroll
  for (int mt = 0; mt < 2; ++mt)
    #pragma unroll
    for (int kc = 0; kc < 4; ++kc)
      qf[mt][kc] = load8(QKV + (size_t)(bb*T_ + q0 + mt*16 + l16)*QSTR + h*D_ + kc*32 + quad*8);

  floatx4 o[2][8];
  #pragma unroll
  for (int mt = 0; mt < 2; ++mt)
    #pragma unroll
    for (int nt = 0; nt < 8; ++nt) o[mt][nt] = (floatx4){0.f, 0.f, 0.f, 0.f};
  float lr[2][4];
  #pragma unroll
  for (int mt = 0; mt < 2; ++mt)
    #pragma unroll
    for (int r = 0; r < 4; ++r) lr[mt][r] = 0.f;

  const int krow_in = lane >> 4;             // 0..3 (K staging row-in-group)
  const int kseg    = lane & 15;             // K staging LDS 16B seg
  const bf16* VTh = VT + (size_t)(bb*HK_ + hk) * D_ * T_;

  const int kb0 = (t0 >= W_) ? (t0 - W_) : 0;
  for (int kb = kb0; kb < t0 + 128; kb += 32) {
    __syncthreads();
    // K: async DMA into seg-swizzled [key][128] (per-lane pre-swizzled source).
    #pragma unroll
    for (int i = 0; i < 2; ++i) {
      const int g = w*2 + i;
      const int krow = g*4 + krow_in;
      const int gseg = (kseg & 8) | ((kseg ^ (krow & 7)) & 7);
      gload_lds16(QKV + (size_t)(bb*T_ + kb + krow)*QSTR + KOFF + hk*D_ + gseg*8,
                  Ks + g*512);
    }
    // V: async DMA from VT rows into linear Vt[d][32] (chunk c -> d=c>>2).
    #pragma unroll
    for (int i = 0; i < 2; ++i) {
      const int c  = (w*2 + i)*64 + lane;    // 16B chunk 0..511
      const int vd = c >> 2, kblk = c & 3;
      gload_lds16(VTh + (size_t)vd*T_ + kb + kblk*8,
                  Vt + (w*2 + i)*512);
    }
    __syncthreads();

    // QK^T: 16 MFMA over the 32-key tile
    floatx4 s[2][2];
    s[0][0] = (floatx4){0.f,0.f,0.f,0.f}; s[0][1] = (floatx4){0.f,0.f,0.f,0.f};
    s[1][0] = (floatx4){0.f,0.f,0.f,0.f}; s[1][1] = (floatx4){0.f,0.f,0.f,0.f};
    #pragma unroll
    for (int kc = 0; kc < 4; ++kc) {
      const int c8 = kc*4 + quad;
      const int s0 = (c8 & 8) | ((c8 ^ (l16 & 7)) & 7);
      bf16x8 bk0 = load8(Ks + l16*128 + s0*8);
      bf16x8 bk1 = load8(Ks + (16 + l16)*128 + s0*8);
      s[0][0] = mfma16(qf[0][kc], bk0, s[0][0]);
      s[0][1] = mfma16(qf[0][kc], bk1, s[0][1]);
      s[1][0] = mfma16(qf[1][kc], bk0, s[1][0]);
      s[1][1] = mfma16(qf[1][kc], bk1, s[1][1]);
    }

    // Fixed-max softmax: p = exp2(s*scale2 - FM), no max tracking at all.
    const float scale2 = 0.12751744f;  // (1/sqrt(128)) * log2(e)
    const float FM     = 16.55f;       // >= max possible |s|*scale2 (16.45)
    #pragma unroll
    for (int mt = 0; mt < 2; ++mt)
      #pragma unroll
      for (int r = 0; r < 4; ++r) {
        const int qg  = q0 + mt*16 + quad*4 + r;
        const int kg0 = kb + l16, kg1 = kb + 16 + l16;
        const float sv0 = (kg0 <= qg && kg0 + W_ >= qg) ? s[mt][0][r]*scale2 - FM : -3.0e38f;
        const float sv1 = (kg1 <= qg && kg1 + W_ >= qg) ? s[mt][1][r]*scale2 - FM : -3.0e38f;
        const float p0 = exp2f(sv0);
        const float p1 = exp2f(sv1);
        lr[mt][r] += p0 + p1;              // per-lane partial; reduced at epilogue
        const int prow = mt*16 + quad*4 + r;
        Ps[w][prow*40 + l16]      = __float2bfloat16(p0);
        Ps[w][prow*40 + 16 + l16] = __float2bfloat16(p1);
      }

    __syncthreads();   // pre-PV barrier: scheduling/register fence (r4 lesson)

    bf16x8 pa0 = load8(&Ps[w][l16*40 + quad*8]);
    bf16x8 pa1 = load8(&Ps[w][(16 + l16)*40 + quad*8]);
    #pragma unroll
    for (int nt = 0; nt < 8; ++nt) {
      const int d = nt*16 + l16;
      bf16x8 bv = load8(Vt + d*32 + quad*8);
      o[0][nt] = mfma16(pa0, bv, o[0][nt]);
      o[1][nt] = mfma16(pa1, bv, o[1][nt]);
    }
  }

  #pragma unroll
  for (int mt = 0; mt < 2; ++mt)
    #pragma unroll
    for (int r = 0; r < 4; ++r) {
      float lt = lr[mt][r];
      #pragma unroll
      for (int off = 1; off < 16; off <<= 1) lt += __shfl_xor(lt, off);
      const float inv = 1.0f / lt;
      const size_t rowoff = (size_t)(bb*T_ + q0 + mt*16 + quad*4 + r) * QSTR + h*D_;
      #pragma unroll
      for (int nt = 0; nt < 8; ++nt)
        QKV[rowoff + nt*16 + l16] = __float2bfloat16(o[mt][nt][r] * inv);
    }
}

extern "C" void kernel_launch(void* const* d_in, const int* in_sizes, int n_in,
                              void* d_out, int out_size, void* d_ws, size_t ws_size,
                              hipStream_t stream) {
  (void)in_sizes; (void)n_in; (void)out_size; (void)ws_size;
  const float* x     = (const float*)d_in[0];
  const float* ve    = (const float*)d_in[1];
  const float* cosb  = (const float*)d_in[2];
  const float* sinb  = (const float*)d_in[3];
  const float* wq    = (const float*)d_in[4];
  const float* wk    = (const float*)d_in[5];
  const float* wv    = (const float*)d_in[6];
  const float* wproj = (const float*)d_in[7];
  const float* wgate = (const float*)d_in[8];

  // ws layout: QKV [BT,4096] (64MB) | wprojb [2048,2048] (8.4MB)
  bf16* QKV    = (bf16*)d_ws;
  bf16* wprojb = QKV + (size_t)BT_ * QSTR;

  // d_out (67.1MB f32) doubles as scratch: xb (33.55) | wqkvb (16.78) |
  // VT (16.78) -- all dead before the final GEMM overwrites d_out.
  bf16* xb    = (bf16*)d_out;
  bf16* wqkvb = xb  + (size_t)BT_ * C_;
  bf16* wqb   = wqkvb;
  bf16* wkb   = wqb + (size_t)C_ * C_;
  bf16* wvb   = wkb + (size_t)(HK_*D_) * C_;
  bf16* VT    = wqkvb + (size_t)QSTR * C_;      // [B*HK][D][T] = 16.78MB

  cvt_k<<<14336, 256, 0, stream>>>(x, wq, wk, wv, wproj, xb, wqb, wkb, wvb, wprojb);
  gemm8<bf16><<<dim3(QSTR/256, BT_/256), 512, 0, stream>>>(xb, wqkvb, QKV,
                                                           BT_, QSTR, C_, C_, QSTR);
  fuse_k<<<BT_, 256, 0, stream>>>(x, ve, cosb, sinb, wgate, QKV);
  vt_k<<<dim3(T_/64, D_/64, B_*HK_), 256, 0, stream>>>(QKV, VT);
  attn_k<<<dim3(T_/128, H_, B_), 256, 0, stream>>>(QKV, VT);
  gemm8<float><<<dim3(C_/256, BT_/256), 512, 0, stream>>>(QKV, wprojb, (float*)d_out,
                                                          BT_, C_, C_, QSTR, C_);
}

// Round 10
// 492.040 us; speedup vs baseline: 1.5754x; 1.0578x over previous
//
#include <hip/hip_runtime.h>
#include <hip/hip_bf16.h>
#include <cstdint>
#include <cstddef>

using bf16 = __hip_bfloat16;
typedef __bf16 bf16x8 __attribute__((ext_vector_type(8)));
typedef float floatx4 __attribute__((ext_vector_type(4)));

#define B_  2
#define T_  4096
#define C_  2048
#define H_  16
#define HK_ 8
#define D_  128
#define W_  512
#define BT_ (B_*T_)
#define QSTR 4096          // row stride of fused QKV buffer
#define KOFF 2048          // K column offset in QKV
#define VOFF 3072          // V column offset in QKV

__device__ __forceinline__ void gload_lds16(const void* g, void* l) {
  __builtin_amdgcn_global_load_lds((const __attribute__((address_space(1))) void*)g,
                                   (__attribute__((address_space(3))) void*)l, 16, 0, 0);
}
__device__ __forceinline__ floatx4 mfma16(bf16x8 a, bf16x8 b, floatx4 c) {
  return __builtin_amdgcn_mfma_f32_16x16x32_bf16(a, b, c, 0, 0, 0);
}
__device__ __forceinline__ __bf16 f2b(float f) {
  union { bf16 h; __bf16 b; } u; u.h = __float2bfloat16(f); return u.b;
}
__device__ __forceinline__ bf16x8 load8(const bf16* p) {
  return *(const bf16x8*)(const void*)p;
}
__device__ __forceinline__ bf16x8 load8(const float* p) {
  float4 a = *(const float4*)(const void*)p;
  float4 b = *(const float4*)(const void*)(p + 4);
  bf16x8 r;
  r[0]=f2b(a.x); r[1]=f2b(a.y); r[2]=f2b(a.z); r[3]=f2b(a.w);
  r[4]=f2b(b.x); r[5]=f2b(b.y); r[6]=f2b(b.z); r[7]=f2b(b.w);
  return r;
}
__device__ __forceinline__ void store1(float* p, float v) { *p = v; }
__device__ __forceinline__ void store1(bf16*  p, float v) { *p = __float2bfloat16(v); }

// One-shot f32 -> bf16 conversion of x and the four weight matrices.
// wq/wk/wv land contiguously -> one [4096, 2048] fused QKV weight.
__global__ __launch_bounds__(256) void cvt_k(const float* __restrict__ x,
                                             const float* __restrict__ wq,
                                             const float* __restrict__ wk,
                                             const float* __restrict__ wv,
                                             const float* __restrict__ wproj,
                                             bf16* __restrict__ xb,
                                             bf16* __restrict__ wqb,
                                             bf16* __restrict__ wkb,
                                             bf16* __restrict__ wvb,
                                             bf16* __restrict__ wprojb) {
  const int b = blockIdx.x;
  const float* src; bf16* dst; size_t off;
  if (b < 8192)       { src = x;     dst = xb;     off = (size_t)b * 2048; }
  else if (b < 10240) { src = wq;    dst = wqb;    off = (size_t)(b-8192) * 2048; }
  else if (b < 11264) { src = wk;    dst = wkb;    off = (size_t)(b-10240) * 2048; }
  else if (b < 12288) { src = wv;    dst = wvb;    off = (size_t)(b-11264) * 2048; }
  else                { src = wproj; dst = wprojb; off = (size_t)(b-12288) * 2048; }
  const size_t i = off + (size_t)threadIdx.x * 8;
  *(bf16x8*)(void*)(dst + i) = load8(src + i);
}

// 256x256-tile deep-pipelined GEMM: C[m][n] = sum_k A[m][k]*B[n][k].
// 8 waves (2M x 4N), BK=64, LDS 128KB double-buffer -> 1 block/CU.
// Round-10 fix vs round-9: ONLY 2 barriers per K-tile. The round-9 per-phase
// barriers (9/tile) protected nothing -- within a tile all waves only READ
// the buffer; hazards exist only at tile boundaries:
//   (a) DMA of tile j complete before any wave reads buf j&1:
//       per-wave vmcnt(8) (own slice) + s_barrier (all slices).
//   (b) All waves' ds_reads of buf j&1 complete before STAGE(j+2) DMA-writes
//       it: explicit s_waitcnt lgkmcnt(0) + s_barrier (s_barrier alone does
//       NOT imply memory completion).
// Counted vmcnt: steady state 16 loads/wave in flight, drain to 8 -- tile
// j+1/j+2 loads stay pending across the whole compute (T4). vmcnt(0) only on
// the last iteration. B-frags read once per tile and held (32 VGPR).
template<typename TC>
__global__ __launch_bounds__(512, 2) void gemm8(const bf16* __restrict__ A,
                                                const bf16* __restrict__ Bw,
                                                TC* __restrict__ Cc,
                                                int M, int N, int Kd,
                                                int lda, int ldc) {
  __shared__ alignas(16) bf16 As[2][256*64];
  __shared__ alignas(16) bf16 Bs[2][256*64];
  const int tid = threadIdx.x;
  const int lane = tid & 63, wid = tid >> 6;
  const int quad = lane >> 4, l16 = lane & 15;
  const int wm = (wid >> 2) * 128;   // wave row block (2 waves in M)
  const int wn = (wid & 3) * 64;     // wave col block (4 waves in N)
  const int m0 = blockIdx.y * 256, n0 = blockIdx.x * 256;
  const int srow = tid >> 3;         // 0..63: staging row within 64-row batch
  const int sseg = tid & 7;          // staging 16B seg within 128B row

  floatx4 acc[8][4];
  #pragma unroll
  for (int i = 0; i < 8; ++i)
    #pragma unroll
    for (int j = 0; j < 4; ++j) acc[i][j] = (floatx4){0.f, 0.f, 0.f, 0.f};

  const int NT = Kd >> 6;

  auto STAGE = [&](int kt, int b) {
    const int k0 = kt << 6;
    bf16* Ad = &As[b][0];
    bf16* Bd = &Bs[b][0];
    #pragma unroll
    for (int i = 0; i < 4; ++i) {
      const int r  = i*64 + srow;                    // tile row 0..255
      const int gs = (sseg ^ (r & 7)) * 8;           // pre-swizzled global seg
      gload_lds16(A  + (size_t)(m0 + r)*lda + k0 + gs, Ad + r*64 + sseg*8);
      gload_lds16(Bw + (size_t)(n0 + r)*Kd  + k0 + gs, Bd + r*64 + sseg*8);
    }
  };

  STAGE(0, 0);
  STAGE(1, 1);

  for (int j = 0; j < NT; ++j) {
    if (j < NT - 1) asm volatile("s_waitcnt vmcnt(8)" ::: "memory");
    else            asm volatile("s_waitcnt vmcnt(0)" ::: "memory");
    __builtin_amdgcn_s_barrier();

    const bf16* Ab = &As[j & 1][0];
    const bf16* Bb = &Bs[j & 1][0];

    __builtin_amdgcn_s_setprio(1);
    bf16x8 bfr[4][2];
    #pragma unroll
    for (int nt = 0; nt < 4; ++nt)
      #pragma unroll
      for (int kk = 0; kk < 2; ++kk) {
        const int n = wn + nt*16 + l16;
        bfr[nt][kk] = load8(Bb + n*64 + (((kk*4 + quad) ^ (n & 7)) * 8));
      }
    #pragma unroll
    for (int mt = 0; mt < 8; ++mt) {
      const int m = wm + mt*16 + l16;
      bf16x8 af0 = load8(Ab + m*64 + ((quad ^ (m & 7)) * 8));
      bf16x8 af1 = load8(Ab + m*64 + (((4 + quad) ^ (m & 7)) * 8));
      #pragma unroll
      for (int nt = 0; nt < 4; ++nt) {
        acc[mt][nt] = mfma16(af0, bfr[nt][0], acc[mt][nt]);
        acc[mt][nt] = mfma16(af1, bfr[nt][1], acc[mt][nt]);
      }
    }
    __builtin_amdgcn_s_setprio(0);

    asm volatile("s_waitcnt lgkmcnt(0)" ::: "memory");
    __builtin_amdgcn_s_barrier();
    if (j + 2 < NT) STAGE(j + 2, j & 1);
  }

  #pragma unroll
  for (int mt = 0; mt < 8; ++mt)
    #pragma unroll
    for (int r = 0; r < 4; ++r) {
      const size_t row = (size_t)(m0 + wm + mt*16 + quad*4 + r);
      #pragma unroll
      for (int nt = 0; nt < 4; ++nt) {
        const int col = n0 + wn + nt*16 + l16;
        store1(Cc + row*ldc + col, acc[mt][nt][r]);
      }
    }
}

// grid (BT), block 256 (4 waves). One block per token, in-place on QKV.
__global__ __launch_bounds__(256) void fuse_k(const float* __restrict__ x,
                                              const float* __restrict__ ve,
                                              const float* __restrict__ cosb,
                                              const float* __restrict__ sinb,
                                              const float* __restrict__ wgate,
                                              bf16* __restrict__ QKV) {
  const int tok = blockIdx.x;
  const int t   = tok & (T_ - 1);
  const int tid = threadIdx.x;
  const int w   = tid >> 6, lane = tid & 63;

  __shared__ float gates[8];

  const float c = cosb[t*64 + lane];
  const float s = sinb[t*64 + lane];
  bf16* rowp = QKV + (size_t)tok * QSTR;

  // RoPE + RMS-norm on 16 Q heads + 8 K heads (6 per wave).
  #pragma unroll
  for (int i = 0; i < 6; ++i) {
    const int j = w*6 + i;
    bf16* base = rowp + ((j < 16) ? j * D_ : (KOFF + (j - 16) * D_));
    const float a = __bfloat162float(base[lane]);
    const float b = __bfloat162float(base[lane + 64]);
    const float lo = a*c + b*s;
    const float hi = b*c - a*s;
    float ss = lo*lo + hi*hi;
    #pragma unroll
    for (int off = 1; off < 64; off <<= 1) ss += __shfl_xor(ss, off);
    const float sc = rsqrtf(ss * (1.0f/128.0f) + 1.1920929e-7f);
    base[lane]      = __float2bfloat16(lo * sc);
    base[lane + 64] = __float2bfloat16(hi * sc);
  }

  // Gate: wave w computes hk = 2w (lanes 0-31) and 2w+1 (lanes 32-63).
  {
    const int hk = w*2 + (lane >> 5);
    const int ch = lane & 31;
    float p = x[(size_t)tok * C_ + ch] * wgate[hk*32 + ch];
    #pragma unroll
    for (int off = 1; off < 32; off <<= 1) p += __shfl_xor(p, off);
    if (ch == 0) gates[hk] = 2.0f / (1.0f + __expf(-p));
  }
  __syncthreads();

  // V += gate * ve : 1024 elems, 4 per thread (float4 ve, ushort4 V).
  {
    const int e0 = tid * 4;
    const float g = gates[e0 >> 7];
    const float4 vv = *(const float4*)(ve + (size_t)tok * (HK_*D_) + e0);
    bf16* vp = rowp + VOFF + e0;
    union { ushort4 u; bf16 h[4]; } uu;
    uu.u = *(const ushort4*)(const void*)vp;
    uu.h[0] = __float2bfloat16(__bfloat162float(uu.h[0]) + g * vv.x);
    uu.h[1] = __float2bfloat16(__bfloat162float(uu.h[1]) + g * vv.y);
    uu.h[2] = __float2bfloat16(__bfloat162float(uu.h[2]) + g * vv.z);
    uu.h[3] = __float2bfloat16(__bfloat162float(uu.h[3]) + g * vv.w);
    *(ushort4*)(void*)vp = uu.u;
  }
}

// V transpose: VT[bb][hk][d][t] = V[bb][t][hk][d] (post gate update).
// grid (T/64, D/64, B*HK), block 256. LDS 64x72 tile (16B-aligned rows).
__global__ __launch_bounds__(256) void vt_k(const bf16* __restrict__ QKV,
                                            bf16* __restrict__ VT) {
  const int t0 = blockIdx.x * 64;
  const int d0 = blockIdx.y * 64;
  const int bh = blockIdx.z;              // bb*8 + hk
  const int bb = bh >> 3, hk = bh & 7;
  const int tid = threadIdx.x;
  __shared__ alignas(16) bf16 Ts[64][72];

  #pragma unroll
  for (int it = 0; it < 2; ++it) {
    const int row = (tid >> 3) + it*32;   // t-local 0..63
    const int c8  = tid & 7;              // d-local 16B seg
    *(bf16x8*)(void*)&Ts[row][c8*8] =
      load8(QKV + (size_t)(bb*T_ + t0 + row)*QSTR + VOFF + hk*D_ + d0 + c8*8);
  }
  __syncthreads();
  #pragma unroll
  for (int it = 0; it < 2; ++it) {
    const int dr   = tid >> 2;            // d-local 0..63
    const int tblk = (tid & 3) + it*4;    // t-local 16B seg 0..7
    union { bf16x8 v; bf16 h[8]; } u;
    #pragma unroll
    for (int e = 0; e < 8; ++e) u.h[e] = Ts[tblk*8 + e][dr];
    *(bf16x8*)(void*)(VT + ((size_t)bh*D_ + d0 + dr)*T_ + t0 + tblk*8) = u.v;
  }
}

// Flash-style windowed attention on fused QKV [BT,4096]. grid (T/128, H, B),
// block 256 (4 waves). 32-key tiles, K and V^T staged by DMA.
// FIXED-MAX softmax: Q,K are RMS-normed so |q·k|*scale*log2e <= 16.45
// (Cauchy-Schwarz). Constant max FM = 16.55: p = exp2(s' - FM); softmax
// shift-invariance makes the output exact; diagonal keeps p well-scaled.
// LDS: Ks 8K + Vt 8K (linear, DMA'd from VT) + Ps 10K = 26 KB.
__global__ __launch_bounds__(256) void attn_k(bf16* QKV,
                                              const bf16* __restrict__ VT) {
  const int t0 = blockIdx.x * 128;
  const int h  = blockIdx.y, bb = blockIdx.z, hk = h >> 1;
  const int tid = threadIdx.x, w = tid >> 6, lane = tid & 63;
  const int quad = lane >> 4, l16 = lane & 15;
  const int q0 = t0 + w * 32;

  __shared__ alignas(16) bf16 Ks[32*128];   // [key][128], seg-XOR swizzled
  __shared__ alignas(16) bf16 Vt[128*32];   // [d][key] linear, from VT
  __shared__ alignas(16) bf16 Ps[4][32*40]; // per-wave P tile, stride 40

  bf16x8 qf[2][4];
  #pragma unroll
  for (int mt = 0; mt < 2; ++mt)
    #pragma unroll
    for (int kc = 0; kc < 4; ++kc)
      qf[mt][kc] = load8(QKV + (size_t)(bb*T_ + q0 + mt*16 + l16)*QSTR + h*D_ + kc*32 + quad*8);

  floatx4 o[2][8];
  #pragma unroll
  for (int mt = 0; mt < 2; ++mt)
    #pragma unroll
    for (int nt = 0; nt < 8; ++nt) o[mt][nt] = (floatx4){0.f, 0.f, 0.f, 0.f};
  float lr[2][4];
  #pragma unroll
  for (int mt = 0; mt < 2; ++mt)
    #pragma unroll
    for (int r = 0; r < 4; ++r) lr[mt][r] = 0.f;

  const int krow_in = lane >> 4;             // 0..3 (K staging row-in-group)
  const int kseg    = lane & 15;             // K staging LDS 16B seg
  const bf16* VTh = VT + (size_t)(bb*HK_ + hk) * D_ * T_;

  const int kb0 = (t0 >= W_) ? (t0 - W_) : 0;
  for (int kb = kb0; kb < t0 + 128; kb += 32) {
    __syncthreads();
    // K: async DMA into seg-swizzled [key][128] (per-lane pre-swizzled source).
    #pragma unroll
    for (int i = 0; i < 2; ++i) {
      const int g = w*2 + i;
      const int krow = g*4 + krow_in;
      const int gseg = (kseg & 8) | ((kseg ^ (krow & 7)) & 7);
      gload_lds16(QKV + (size_t)(bb*T_ + kb + krow)*QSTR + KOFF + hk*D_ + gseg*8,
                  Ks + g*512);
    }
    // V: async DMA from VT rows into linear Vt[d][32] (chunk c -> d=c>>2).
    #pragma unroll
    for (int i = 0; i < 2; ++i) {
      const int c  = (w*2 + i)*64 + lane;    // 16B chunk 0..511
      const int vd = c >> 2, kblk = c & 3;
      gload_lds16(VTh + (size_t)vd*T_ + kb + kblk*8,
                  Vt + (w*2 + i)*512);
    }
    __syncthreads();

    // QK^T: 16 MFMA over the 32-key tile
    floatx4 s[2][2];
    s[0][0] = (floatx4){0.f,0.f,0.f,0.f}; s[0][1] = (floatx4){0.f,0.f,0.f,0.f};
    s[1][0] = (floatx4){0.f,0.f,0.f,0.f}; s[1][1] = (floatx4){0.f,0.f,0.f,0.f};
    #pragma unroll
    for (int kc = 0; kc < 4; ++kc) {
      const int c8 = kc*4 + quad;
      const int s0 = (c8 & 8) | ((c8 ^ (l16 & 7)) & 7);
      bf16x8 bk0 = load8(Ks + l16*128 + s0*8);
      bf16x8 bk1 = load8(Ks + (16 + l16)*128 + s0*8);
      s[0][0] = mfma16(qf[0][kc], bk0, s[0][0]);
      s[0][1] = mfma16(qf[0][kc], bk1, s[0][1]);
      s[1][0] = mfma16(qf[1][kc], bk0, s[1][0]);
      s[1][1] = mfma16(qf[1][kc], bk1, s[1][1]);
    }

    // Fixed-max softmax: p = exp2(s*scale2 - FM), no max tracking at all.
    const float scale2 = 0.12751744f;  // (1/sqrt(128)) * log2(e)
    const float FM     = 16.55f;       // >= max possible |s|*scale2 (16.45)
    #pragma unroll
    for (int mt = 0; mt < 2; ++mt)
      #pragma unroll
      for (int r = 0; r < 4; ++r) {
        const int qg  = q0 + mt*16 + quad*4 + r;
        const int kg0 = kb + l16, kg1 = kb + 16 + l16;
        const float sv0 = (kg0 <= qg && kg0 + W_ >= qg) ? s[mt][0][r]*scale2 - FM : -3.0e38f;
        const float sv1 = (kg1 <= qg && kg1 + W_ >= qg) ? s[mt][1][r]*scale2 - FM : -3.0e38f;
        const float p0 = exp2f(sv0);
        const float p1 = exp2f(sv1);
        lr[mt][r] += p0 + p1;              // per-lane partial; reduced at epilogue
        const int prow = mt*16 + quad*4 + r;
        Ps[w][prow*40 + l16]      = __float2bfloat16(p0);
        Ps[w][prow*40 + 16 + l16] = __float2bfloat16(p1);
      }

    __syncthreads();   // pre-PV barrier: scheduling/register fence (r4 lesson)

    bf16x8 pa0 = load8(&Ps[w][l16*40 + quad*8]);
    bf16x8 pa1 = load8(&Ps[w][(16 + l16)*40 + quad*8]);
    #pragma unroll
    for (int nt = 0; nt < 8; ++nt) {
      const int d = nt*16 + l16;
      bf16x8 bv = load8(Vt + d*32 + quad*8);
      o[0][nt] = mfma16(pa0, bv, o[0][nt]);
      o[1][nt] = mfma16(pa1, bv, o[1][nt]);
    }
  }

  #pragma unroll
  for (int mt = 0; mt < 2; ++mt)
    #pragma unroll
    for (int r = 0; r < 4; ++r) {
      float lt = lr[mt][r];
      #pragma unroll
      for (int off = 1; off < 16; off <<= 1) lt += __shfl_xor(lt, off);
      const float inv = 1.0f / lt;
      const size_t rowoff = (size_t)(bb*T_ + q0 + mt*16 + quad*4 + r) * QSTR + h*D_;
      #pragma unroll
      for (int nt = 0; nt < 8; ++nt)
        QKV[rowoff + nt*16 + l16] = __float2bfloat16(o[mt][nt][r] * inv);
    }
}

extern "C" void kernel_launch(void* const* d_in, const int* in_sizes, int n_in,
                              void* d_out, int out_size, void* d_ws, size_t ws_size,
                              hipStream_t stream) {
  (void)in_sizes; (void)n_in; (void)out_size; (void)ws_size;
  const float* x     = (const float*)d_in[0];
  const float* ve    = (const float*)d_in[1];
  const float* cosb  = (const float*)d_in[2];
  const float* sinb  = (const float*)d_in[3];
  const float* wq    = (const float*)d_in[4];
  const float* wk    = (const float*)d_in[5];
  const float* wv    = (const float*)d_in[6];
  const float* wproj = (const float*)d_in[7];
  const float* wgate = (const float*)d_in[8];

  // ws layout: QKV [BT,4096] (64MB) | wprojb [2048,2048] (8.4MB)
  bf16* QKV    = (bf16*)d_ws;
  bf16* wprojb = QKV + (size_t)BT_ * QSTR;

  // d_out (67.1MB f32) doubles as scratch: xb (33.55) | wqkvb (16.78) |
  // VT (16.78) -- all dead before the final GEMM overwrites d_out.
  bf16* xb    = (bf16*)d_out;
  bf16* wqkvb = xb  + (size_t)BT_ * C_;
  bf16* wqb   = wqkvb;
  bf16* wkb   = wqb + (size_t)C_ * C_;
  bf16* wvb   = wkb + (size_t)(HK_*D_) * C_;
  bf16* VT    = wqkvb + (size_t)QSTR * C_;      // [B*HK][D][T] = 16.78MB

  cvt_k<<<14336, 256, 0, stream>>>(x, wq, wk, wv, wproj, xb, wqb, wkb, wvb, wprojb);
  gemm8<bf16><<<dim3(QSTR/256, BT_/256), 512, 0, stream>>>(xb, wqkvb, QKV,
                                                           BT_, QSTR, C_, C_, QSTR);
  fuse_k<<<BT_, 256, 0, stream>>>(x, ve, cosb, sinb, wgate, QKV);
  vt_k<<<dim3(T_/64, D_/64, B_*HK_), 256, 0, stream>>>(QKV, VT);
  attn_k<<<dim3(T_/128, H_, B_), 256, 0, stream>>>(QKV, VT);
  gemm8<float><<<dim3(C_/256, BT_/256), 512, 0, stream>>>(QKV, wprojb, (float*)d_out,
                                                          BT_, C_, C_, QSTR, C_);
}